// Round 6
// baseline (1621.410 us; speedup 1.0000x reference)
//
#include <hip/hip_runtime.h>
#include <stdint.h>

typedef unsigned int u32;
typedef unsigned short u16;
typedef _Float16 f16;
typedef _Float16 f16x8 __attribute__((ext_vector_type(8)));
typedef _Float16 f16x4 __attribute__((ext_vector_type(4)));
typedef _Float16 f16x2 __attribute__((ext_vector_type(2)));
typedef float f32x4 __attribute__((ext_vector_type(4)));

constexpr int NB = 4096;   // batch
constexpr int NT = 56;     // encoder steps
constexpr int NS = 28;     // decoder steps
constexpr int NH = 126;    // hidden
constexpr int NHP = 128;
constexpr float LOG2E = 1.4426950408889634f;

// encT (j-major enc for p3): [b][jp 0..63][t 0..55] f16x2
constexpr int TJP = 120;    // f16 per jp row (56 t * 2 + pad)
constexpr int TB  = 7712;   // f16 per batch (64*120 + pad)

// workspace offsets (bytes)
constexpr size_t OFF_H    = 0;                    // f32[4096*128] h state (pads 0)
constexpr size_t OFF_ENC  = 2097152;              // f16[4096*56*128] enc_out [b][t][h]
constexpr size_t OFF_UO   = OFF_ENC + 58720256;   // f16[4096*56*128] EU=e^(2*Uo) [b][t][h]
constexpr size_t OFF_WENC = OFF_UO + 58720256;    // f16[384*160]  enc gates [x20+pad|h128]
constexpr size_t OFF_WDEC = OFF_WENC + 122880;    // f16[384*288]  dec gates [head16+pad|attn128|h128]
constexpr size_t OFF_WL   = OFF_WDEC + 221184;    // f16[128*128]  Wl
constexpr size_t OFF_UW   = OFF_WL + 32768;       // f16[128*128]  U_W

__device__ __forceinline__ float fexp2(float x){ return __builtin_amdgcn_exp2f(x); }
__device__ __forceinline__ float frcp (float x){ return __builtin_amdgcn_rcpf(x); }
__device__ __forceinline__ float sigm (float x){ return frcp(1.f + fexp2(-LOG2E * x)); }
__device__ __forceinline__ float ftanh(float x){ return 1.f - 2.f * frcp(1.f + fexp2(2.f * LOG2E * x)); }

// ---------------- weight repack ----------------
__global__ void k_prep(const float* __restrict__ eWih, const float* __restrict__ eWhh,
                       const float* __restrict__ dWih, const float* __restrict__ dWhh,
                       const float* __restrict__ UW,   const float* __restrict__ Wl,
                       char* __restrict__ ws)
{
  f16* wenc = (f16*)(ws + OFF_WENC);
  f16* wdec = (f16*)(ws + OFF_WDEC);
  f16* wl   = (f16*)(ws + OFF_WL);
  f16* uw   = (f16*)(ws + OFF_UW);
  const int nE = 384 * 160, nD = 384 * 288, nW = 128 * 128;
  const int total = nE + nD + nW + nW;
  for (int i = blockIdx.x * 256 + threadIdx.x; i < total; i += gridDim.x * 256) {
    int idx = i;
    if (idx < nE) {
      const int r = idx / 160, c = idx % 160;
      float v = 0.f;
      if (r < 378) {
        if (c < 20) v = eWih[r * 20 + c];
        else if (c >= 32 && c < 158) v = eWhh[r * 126 + (c - 32)];
      }
      wenc[idx] = (f16)v; continue;
    }
    idx -= nE;
    if (idx < nD) {
      const int r = idx / 288, c = idx % 288;
      float v = 0.f;
      if (r < 378) {
        if (c < 16) v = dWih[r * 142 + c];
        else if (c >= 32 && c < 158) v = dWih[r * 142 + 16 + (c - 32)];
        else if (c >= 160 && c < 286) v = dWhh[r * 126 + (c - 160)];
      }
      wdec[idx] = (f16)v; continue;
    }
    idx -= nD;
    if (idx < nW) {
      const int r = idx >> 7, c = idx & 127;
      wl[idx] = (f16)((r < 126 && c < 126) ? Wl[r * 126 + c] : 0.f);
      continue;
    }
    idx -= nW;
    { const int r = idx >> 7, c = idx & 127;
      uw[idx] = (f16)((r < 126 && c < 126) ? UW[r * 126 + c] : 0.f); }
  }
}

// ---------------- init MLP ----------------
__global__ __launch_bounds__(256) void k_mlp(
    const float* __restrict__ ann, const float* __restrict__ W1, const float* __restrict__ b1,
    const float* __restrict__ W2, const float* __restrict__ b2, float* __restrict__ hstate)
{
  __shared__ float anns[32][33];
  __shared__ float t1s[32][101];
  const int tid = threadIdx.x;
  const int b0 = blockIdx.x * 32;
  for (int i = tid; i < 32 * 30; i += 256)
    anns[i / 30][i % 30] = ann[(b0 + i / 30) * 30 + (i % 30)];
  __syncthreads();
  const int b = tid & 31, rg = tid >> 5;
  for (int m = rg; m < 96; m += 8) {
    float a = b1[m];
    for (int k = 0; k < 30; ++k) a += W1[m * 30 + k] * anns[b][k];
    t1s[b][m] = fmaxf(a, 0.f);
  }
  __syncthreads();
  for (int j = rg; j < NHP; j += 8) {
    float a = 0.f;
    if (j < NH) {
      a = b2[j];
      for (int k = 0; k < 96; ++k) a += W2[j * 96 + k] * t1s[b][k];
    }
    hstate[(b0 + b) * NHP + j] = a;
  }
}

// ---------------- encoder: MFMA, reg-resident weights, M=16, h double-buffered ----------------
// Stores enc_out (f16) and EU = e^(2*Uo) (f16).
__global__ __launch_bounds__(512) void k_enc(
    const float* __restrict__ xenc, const f16* __restrict__ Wenc,
    const f16* __restrict__ Uw,
    const float* __restrict__ bih, const float* __restrict__ bhh,
    const float* __restrict__ Ub,
    float* __restrict__ hstate, f16* __restrict__ encO, u16* __restrict__ uoO)
{
  __shared__ f16 av[16][296];   // [b][ x20+pad12 | h_p0 128 | h_p1 128 | pad ]
  const int tid = threadIdx.x;
  const int wid = tid >> 6, l = tid & 63, quad = l >> 4, col = l & 15;
  const int b0 = blockIdx.x * 16;
  const int jb = wid * 16, j = jb + col;
  const bool valid = j < NH;
  const int jc = valid ? j : NH - 1;

  const float br  = bih[jc]        + bhh[jc];
  const float bz  = bih[NH + jc]   + bhh[NH + jc];
  const float bnx = bih[2*NH + jc];
  const float bnh = bhh[2*NH + jc];
  const float ub  = Ub[jc];

  f16x8 rB[5], zB[5], nxB, nhB[4], uB[4];
  {
    const int ko = quad * 8, rr = jb + col;
#pragma unroll
    for (int kt = 0; kt < 5; ++kt) {
      rB[kt] = *(const f16x8*)&Wenc[rr * 160 + kt * 32 + ko];
      zB[kt] = *(const f16x8*)&Wenc[(NH + rr) * 160 + kt * 32 + ko];
    }
    nxB = *(const f16x8*)&Wenc[(2*NH + rr) * 160 + ko];
#pragma unroll
    for (int kt = 0; kt < 4; ++kt) {
      nhB[kt] = *(const f16x8*)&Wenc[(2*NH + rr) * 160 + 32 + kt * 32 + ko];
      uB[kt]  = *(const f16x8*)&Uw[rr * 128 + kt * 32 + ko];
    }
  }

  {
    const int bb = tid >> 5, c4 = (tid & 31) * 4;
    const float4 hv = *(const float4*)&hstate[(b0 + bb) * NHP + c4];
    av[bb][32 + c4]     = (f16)hv.x; av[bb][32 + c4 + 1] = (f16)hv.y;
    av[bb][32 + c4 + 2] = (f16)hv.z; av[bb][32 + c4 + 3] = (f16)hv.w;
  }
  if (tid < 192) { const int bb = tid / 12, p = tid % 12; av[bb][20 + p] = (f16)0.f; }
  __syncthreads();

  const int m = col, ko = quad * 8;
  for (int t = 0; t < NT; ++t) {
    const int hp = 32 + (t & 1) * 128, hq = 32 + ((t + 1) & 1) * 128;
    if (tid < 320) {
      const int bb = tid / 20, e = tid % 20;
      av[bb][e] = (f16)xenc[((size_t)t * NB + b0 + bb) * 20 + e];
    }
    __syncthreads();                       // B1
    f16x8 A[5];
    A[0] = *(const f16x8*)&av[m][ko];
#pragma unroll
    for (int kt = 1; kt < 5; ++kt) A[kt] = *(const f16x8*)&av[m][hp + (kt - 1) * 32 + ko];

    f32x4 Cr = {br, br, br, br}, Cz = {bz, bz, bz, bz};
    f32x4 Cnx = {bnx, bnx, bnx, bnx}, Cnh = {bnh, bnh, bnh, bnh};
#pragma unroll
    for (int kt = 0; kt < 5; ++kt) {
      Cr = __builtin_amdgcn_mfma_f32_16x16x32_f16(A[kt], rB[kt], Cr, 0, 0, 0);
      Cz = __builtin_amdgcn_mfma_f32_16x16x32_f16(A[kt], zB[kt], Cz, 0, 0, 0);
    }
    Cnx = __builtin_amdgcn_mfma_f32_16x16x32_f16(A[0], nxB, Cnx, 0, 0, 0);
#pragma unroll
    for (int kt = 0; kt < 4; ++kt)
      Cnh = __builtin_amdgcn_mfma_f32_16x16x32_f16(A[kt + 1], nhB[kt], Cnh, 0, 0, 0);

    float hv4[4];
#pragma unroll
    for (int c = 0; c < 4; ++c) {
      const int bb = quad * 4 + c;
      const float hold = (float)av[bb][hp + j];
      const float r = sigm(Cr[c]), z = sigm(Cz[c]);
      const float n = ftanh(Cnx[c] + r * Cnh[c]);
      hv4[c] = (1.f - z) * n + z * hold;
    }
#pragma unroll
    for (int c = 0; c < 4; ++c) {
      const int bb = quad * 4 + c;
      const f16 hs = valid ? (f16)hv4[c] : (f16)0.f;
      av[bb][hq + j] = hs;
      encO[((size_t)(b0 + bb) * NT + t) * 128 + j] = hs;
    }
    if (t == NT - 1 && valid) {
#pragma unroll
      for (int c = 0; c < 4; ++c)
        hstate[(b0 + quad * 4 + c) * NHP + j] = hv4[c];
    }
    __syncthreads();                       // B2

    f16x8 Ah[4];
#pragma unroll
    for (int kt = 0; kt < 4; ++kt) Ah[kt] = *(const f16x8*)&av[m][hq + kt * 32 + ko];
    f32x4 Cu = {ub, ub, ub, ub};
#pragma unroll
    for (int kt = 0; kt < 4; ++kt)
      Cu = __builtin_amdgcn_mfma_f32_16x16x32_f16(Ah[kt], uB[kt], Cu, 0, 0, 0);
#pragma unroll
    for (int c = 0; c < 4; ++c) {
      union { f16 h; u16 u; } cv;
      cv.h = (f16)fexp2(2.f * LOG2E * Cu[c]);           // EU = e^(2*Uo), f16
      uoO[((size_t)(b0 + quad * 4 + c) * NT + t) * 128 + j] = valid ? cv.u : (u16)0;
    }
  }
}

// ---------------- decoder: M=4 at A-rows {0,4,8,12}, 512 threads ---------------------------
// LDS ~69 KB (enc only) -> 2 blocks/CU co-resident -> 4 waves/SIMD: independent blocks hide
// each other's barrier/dep stalls. EU read from global/L2 in p2 (256B segments per 8-lane
// group, 1-round prefetch; per-XCD resident EU = 64 blocks x 56KB = 3.6MB <= 4MB L2).
__global__ __launch_bounds__(512, 4) void k_dec(
    const float* __restrict__ xdec, const float* __restrict__ xenc,
    const f16* __restrict__ Wdec, const f16* __restrict__ WlW,
    const float* __restrict__ bih, const float* __restrict__ bhh,
    const float* __restrict__ Wlb, const float* __restrict__ Vw,
    const float* __restrict__ Vb, const float* __restrict__ how,
    const float* __restrict__ hob, const float* __restrict__ hstate,
    const f16* __restrict__ encO, const u16* __restrict__ uoO,
    float* __restrict__ out)
{
  __shared__ __align__(16) f16 encT[4 * TB];     // enc f16, 61.7 KB, j-major
  __shared__ __align__(16) f16 av[5][424];       // [b][head16+pad16|attn128|h_p0|h_p1|pad]; row4=0
  __shared__ float EWS[4][132];                  // e^(2*Wh)
  __shared__ float scS[4][60];                   // exp(score)
  __shared__ __align__(16) f16 hows16[128];
  const int tid = threadIdx.x;
  const int wid = tid >> 6, l = tid & 63, quad = l >> 4, col = l & 15;
  const int b0 = blockIdx.x * 4;
  const int jb = wid * 16, j = jb + col;
  const bool valid = j < NH;
  const int jc = valid ? j : NH - 1;

  const float br  = bih[jc]        + bhh[jc];
  const float bz  = bih[NH + jc]   + bhh[NH + jc];
  const float bnx = bih[2*NH + jc];
  const float bnh = bhh[2*NH + jc];
  const float wb  = Wlb[jc];
  const float vb0 = Vb[0], hob0 = hob[0];

  f16x8 rB[9], zB[9], nxB[5], nhB[4], wlB[4];
  {
    const int ko = quad * 8, rr = jb + col;
#pragma unroll
    for (int kt = 0; kt < 9; ++kt) {
      rB[kt] = *(const f16x8*)&Wdec[rr * 288 + kt * 32 + ko];
      zB[kt] = *(const f16x8*)&Wdec[(NH + rr) * 288 + kt * 32 + ko];
    }
#pragma unroll
    for (int kt = 0; kt < 5; ++kt)
      nxB[kt] = *(const f16x8*)&Wdec[(2*NH + rr) * 288 + kt * 32 + ko];
#pragma unroll
    for (int kt = 0; kt < 4; ++kt) {
      nhB[kt] = *(const f16x8*)&Wdec[(2*NH + rr) * 288 + 160 + kt * 32 + ko];
      wlB[kt] = *(const f16x8*)&WlW[rr * 128 + kt * 32 + ko];
    }
  }

  const int g = tid >> 3, sub = tid & 7;
  float n2v[16], svsum = 0.f;
#pragma unroll
  for (int i = 0; i < 16; ++i) {
    const int jj = sub * 16 + i;
    const float v = (jj < NH) ? Vw[jj] : 0.f;
    n2v[i] = -2.f * v;
    svsum += v;
  }
  if (tid >= 256 && tid < 384) {
    const int q = tid - 256; hows16[q] = (f16)((q < NH) ? how[q] : 0.f);
  }
  for (int i = tid; i < 5 * 424; i += 512) av[i / 424][i % 424] = (f16)0.f;
  if (tid < 24) EWS[tid / 6][126 + tid % 6] = 0.f;   // pad cols stay 0 (avoid NaN)
  {
    const size_t gb = (size_t)b0 * NT * 128;
    for (int i = tid; i < 4 * NT * 16; i += 512) {
      const int ch = i & 15, btr = i >> 4;
      const int bb = btr / NT, tt = btr % NT;
      const f16x8 ev = *(const f16x8*)&encO[gb + (size_t)btr * 128 + ch * 8];
#pragma unroll
      for (int k2 = 0; k2 < 4; ++k2) {   // transpose to j-major: jp = ch*4+k2
        f16x2 pr; pr[0] = ev[2 * k2]; pr[1] = ev[2 * k2 + 1];
        *(f16x2*)&encT[bb * TB + (ch * 4 + k2) * TJP + tt * 2] = pr;
      }
    }
  }
  __syncthreads();
  if (tid < 128) {   // h0 rows 0..3 into parity-0 [160..288)
    const int bb = tid >> 5, c4 = (tid & 31) * 4;
    const float4 hv = *(const float4*)&hstate[(b0 + bb) * NHP + c4];
    av[bb][160 + c4]     = (f16)hv.x; av[bb][160 + c4 + 1] = (f16)hv.y;
    av[bb][160 + c4 + 2] = (f16)hv.z; av[bb][160 + c4 + 3] = (f16)hv.w;
  }
  if (tid < 4) av[tid][0] = (f16)xenc[((size_t)(NT - 1) * NB + b0 + tid) * 20];  // gt0
  __syncthreads();

  const int m = col, ko = quad * 8;
  // batch b feeds A-row 4b; rows with m%4!=0 read the zero row 4
  const int arow = ((m & 3) == 0) ? (m >> 2) : 4;
  const int pb = tid & 3, pth = (tid >> 2) & 1, pjp = tid >> 3;   // p3 map
  // p2: EU global base for this thread's (batch, h-slice)
  const u16* eub = uoO + (size_t)(b0 + (g & 3)) * NT * 128 + sub * 16;

  for (int s = 0; s < NS; ++s) {
    const int hp = 160 + (s & 1) * 128, hq = 160 + ((s + 1) & 1) * 128;

    // p1: Wh -> EW = e^(2*Wh) (MFMA); merged p5 (out for step s-1) on wave 0; stage dec_x.
    {
      f16x8 Ah[4];
#pragma unroll
      for (int kt = 0; kt < 4; ++kt) Ah[kt] = *(const f16x8*)&av[arow][hp + kt * 32 + ko];
      f32x4 Cw = {wb, wb, wb, wb};
#pragma unroll
      for (int kt = 0; kt < 4; ++kt)
        Cw = __builtin_amdgcn_mfma_f32_16x16x32_f16(Ah[kt], wlB[kt], Cw, 0, 0, 0);
      if (valid) EWS[quad][j] = fexp2(2.f * LOG2E * Cw[0]);
      if (wid == 0 && s > 0) {           // p5 for previous step: hp(s) == hq(s-1)
        f16x8 hB[4];
        const f16x8 zz = {};
#pragma unroll
        for (int kt = 0; kt < 4; ++kt)
          hB[kt] = (col == 0) ? *(const f16x8*)&hows16[kt * 32 + ko] : zz;
        f32x4 Co = {0.f, 0.f, 0.f, 0.f};
#pragma unroll
        for (int kt = 0; kt < 4; ++kt)
          Co = __builtin_amdgcn_mfma_f32_16x16x32_f16(Ah[kt], hB[kt], Co, 0, 0, 0);
        if (col == 0) {
          const float o = Co[0] + hob0;
          out[(size_t)(s - 1) * NB + b0 + quad] = o;
          av[quad][0] = (f16)o;          // prev feedback; ordered by B1..B3 before p4
        }
      }
    }
    if (tid < 60) { const int bb = tid / 15, e = tid % 15;
      av[bb][1 + e] = (f16)xdec[((size_t)s * NB + b0 + bb) * 15 + e]; }
    __syncthreads();  // B1

    // p2: scores via svsum + sum(-2v/(1+EU*EW)); 64 groups = 4b x 16 t-base, 4 rounds
    // into rs[4]; EU from global/L2, 1-round prefetch; one interleaved reduce tree.
    {
      const int sbb = g & 3, tb = g >> 2;
      float ew[16];
#pragma unroll
      for (int i = 0; i < 4; ++i)
        *(float4*)&ew[i * 4] = *(const float4*)&EWS[sbb][sub * 16 + i * 4];
      uint4 q0 = *(const uint4*)&eub[(size_t)tb * 128];
      uint4 q1 = *(const uint4*)&eub[(size_t)tb * 128 + 8];
      float rs[4];
#pragma unroll
      for (int rd = 0; rd < 4; ++rd) {
        const int t = rd * 16 + tb;
        const u32 wsv[8] = {q0.x, q0.y, q0.z, q0.w, q1.x, q1.y, q1.z, q1.w};
        if (rd < 3) {
          const int tn = (t + 16 < NT) ? (t + 16) : (NT - 1);
          q0 = *(const uint4*)&eub[(size_t)tn * 128];
          q1 = *(const uint4*)&eub[(size_t)tn * 128 + 8];
        }
        float ac0 = 0.f, ac1 = 0.f, ac2 = 0.f, ac3 = 0.f;
#pragma unroll
        for (int k = 0; k < 8; k += 2) {
          union { u32 i; f16x2 h; } ua, ub2;
          ua.i = wsv[k]; ub2.i = wsv[k + 1];
          const float p0 = fmaf((float)ua.h[0],  ew[2 * k],     1.f);
          const float p1 = fmaf((float)ua.h[1],  ew[2 * k + 1], 1.f);
          const float p2 = fmaf((float)ub2.h[0], ew[2 * k + 2], 1.f);
          const float p3 = fmaf((float)ub2.h[1], ew[2 * k + 3], 1.f);
          ac0 = fmaf(n2v[2 * k],     frcp(p0), ac0);
          ac1 = fmaf(n2v[2 * k + 1], frcp(p1), ac1);
          ac2 = fmaf(n2v[2 * k + 2], frcp(p2), ac2);
          ac3 = fmaf(n2v[2 * k + 3], frcp(p3), ac3);
        }
        rs[rd] = svsum + (ac0 + ac1) + (ac2 + ac3);
      }
      rs[0] += __shfl_xor(rs[0], 1, 64);
      rs[1] += __shfl_xor(rs[1], 1, 64);
      rs[2] += __shfl_xor(rs[2], 1, 64);
      rs[3] += __shfl_xor(rs[3], 1, 64);
      rs[0] += __shfl_xor(rs[0], 2, 64);
      rs[1] += __shfl_xor(rs[1], 2, 64);
      rs[2] += __shfl_xor(rs[2], 2, 64);
      rs[3] += __shfl_xor(rs[3], 2, 64);
      rs[0] += __shfl_xor(rs[0], 4, 64);
      rs[1] += __shfl_xor(rs[1], 4, 64);
      rs[2] += __shfl_xor(rs[2], 4, 64);
      rs[3] += __shfl_xor(rs[3], 4, 64);
      if (sub == 0) {
#pragma unroll
        for (int rd = 0; rd < 4; ++rd) {
          const int t = rd * 16 + tb;
          if (t < NT) scS[sbb][t] = fexp2(LOG2E * (rs[rd] + vb0));
        }
      }
    }
    __syncthreads();  // B2

    // p3: softmax + attn; thread = (batch, pth t-half, j-pair); 7 wide b128 reads of encT
    {
      const int j0 = pjp * 2;
      const f16* er = &encT[pb * TB + pjp * TJP + pth * 56];
      const float* scp = &scS[pb][pth * 28];
      float Za = 0.f, Zb = 0.f;
      float a0a = 0.f, a0b = 0.f, a1a = 0.f, a1b = 0.f;
#pragma unroll
      for (int it = 0; it < 7; ++it) {
        const f16x8 ev = *(const f16x8*)&er[it * 8];
        const float4 sc = *(const float4*)&scp[it * 4];
        Za += sc.x; Zb += sc.y; Za += sc.z; Zb += sc.w;
        a0a = fmaf(sc.x, (float)ev[0], a0a);
        a1a = fmaf(sc.x, (float)ev[1], a1a);
        a0b = fmaf(sc.y, (float)ev[2], a0b);
        a1b = fmaf(sc.y, (float)ev[3], a1b);
        a0a = fmaf(sc.z, (float)ev[4], a0a);
        a1a = fmaf(sc.z, (float)ev[5], a1a);
        a0b = fmaf(sc.w, (float)ev[6], a0b);
        a1b = fmaf(sc.w, (float)ev[7], a1b);
      }
      float Z = Za + Zb, a0 = a0a + a0b, a1 = a1a + a1b;
      a0 += __shfl_xor(a0, 4, 64);
      a1 += __shfl_xor(a1, 4, 64);
      Z  += __shfl_xor(Z, 4, 64);
      if (pth == 0) {
        const float inv = frcp(Z);
        f16x2 st; st[0] = (f16)(a0 * inv); st[1] = (f16)(a1 * inv);
        *(f16x2*)&av[pb][32 + j0] = st;
      }
    }
    __syncthreads();  // B3

    // p4: GRU gates (MFMA) + state update; every lane handles one (batch=quad, j) elem
    {
      f16x8 A[9];
#pragma unroll
      for (int kt = 0; kt < 5; ++kt) A[kt] = *(const f16x8*)&av[arow][kt * 32 + ko];
#pragma unroll
      for (int kt = 5; kt < 9; ++kt) A[kt] = *(const f16x8*)&av[arow][hp + (kt - 5) * 32 + ko];
      f32x4 Cr = {br, br, br, br}, Cz = {bz, bz, bz, bz};
      f32x4 Cnx = {bnx, bnx, bnx, bnx}, Cnh = {bnh, bnh, bnh, bnh};
#pragma unroll
      for (int kt = 0; kt < 9; ++kt) {
        Cr = __builtin_amdgcn_mfma_f32_16x16x32_f16(A[kt], rB[kt], Cr, 0, 0, 0);
        Cz = __builtin_amdgcn_mfma_f32_16x16x32_f16(A[kt], zB[kt], Cz, 0, 0, 0);
      }
#pragma unroll
      for (int kt = 0; kt < 5; ++kt)
        Cnx = __builtin_amdgcn_mfma_f32_16x16x32_f16(A[kt], nxB[kt], Cnx, 0, 0, 0);
#pragma unroll
      for (int kt = 0; kt < 4; ++kt)
        Cnh = __builtin_amdgcn_mfma_f32_16x16x32_f16(A[kt + 5], nhB[kt], Cnh, 0, 0, 0);
      {
        const float hold = (float)av[quad][hp + j];
        const float r = sigm(Cr[0]), z = sigm(Cz[0]);
        const float n = ftanh(Cnx[0] + r * Cnh[0]);
        const float h2 = (1.f - z) * n + z * hold;
        if (valid) av[quad][hq + j] = (f16)h2;
      }
    }
    __syncthreads();  // B4
  }

  // epilogue p5 for s = NS-1 (B4 of last iter orders p4 writes before these reads)
  if (wid == 0) {
    const int hql = 160 + (NS & 1) * 128;
    f16x8 Ah2[4], hB[4];
    const f16x8 zz = {};
#pragma unroll
    for (int kt = 0; kt < 4; ++kt) {
      Ah2[kt] = *(const f16x8*)&av[arow][hql + kt * 32 + ko];
      hB[kt] = (col == 0) ? *(const f16x8*)&hows16[kt * 32 + ko] : zz;
    }
    f32x4 Co = {0.f, 0.f, 0.f, 0.f};
#pragma unroll
    for (int kt = 0; kt < 4; ++kt)
      Co = __builtin_amdgcn_mfma_f32_16x16x32_f16(Ah2[kt], hB[kt], Co, 0, 0, 0);
    if (col == 0) out[(size_t)(NS - 1) * NB + b0 + quad] = Co[0] + hob0;
  }
}

extern "C" void kernel_launch(void* const* d_in, const int* in_sizes, int n_in,
                              void* d_out, int out_size, void* d_ws, size_t ws_size,
                              hipStream_t stream)
{
  const float* ann   = (const float*)d_in[0];
  const float* xenc  = (const float*)d_in[1];
  const float* xdec  = (const float*)d_in[2];
  const float* W1    = (const float*)d_in[3];
  const float* b1    = (const float*)d_in[4];
  const float* W2    = (const float*)d_in[5];
  const float* b2    = (const float*)d_in[6];
  const float* eWih  = (const float*)d_in[7];
  const float* eWhh  = (const float*)d_in[8];
  const float* ebih  = (const float*)d_in[9];
  const float* ebhh  = (const float*)d_in[10];
  const float* dWih  = (const float*)d_in[11];
  const float* dWhh  = (const float*)d_in[12];
  const float* dbih  = (const float*)d_in[13];
  const float* dbhh  = (const float*)d_in[14];
  const float* UW    = (const float*)d_in[15];
  const float* Ubias = (const float*)d_in[16];
  const float* Wl    = (const float*)d_in[17];
  const float* Wlb   = (const float*)d_in[18];
  const float* Vw    = (const float*)d_in[19];
  const float* Vb    = (const float*)d_in[20];
  const float* how   = (const float*)d_in[21];
  const float* hob   = (const float*)d_in[22];

  char* ws = (char*)d_ws;
  float* hstate = (float*)(ws + OFF_H);
  f16*   encB   = (f16*)(ws + OFF_ENC);
  u16*   uoB    = (u16*)(ws + OFF_UO);
  const f16* pWenc = (const f16*)(ws + OFF_WENC);
  const f16* pWdec = (const f16*)(ws + OFF_WDEC);
  const f16* pWl   = (const f16*)(ws + OFF_WL);
  const f16* pUW   = (const f16*)(ws + OFF_UW);

  k_prep<<<200, 256, 0, stream>>>(eWih, eWhh, dWih, dWhh, UW, Wl, ws);
  k_mlp <<<128, 256, 0, stream>>>(ann, W1, b1, W2, b2, hstate);
  k_enc <<<NB / 16, 512, 0, stream>>>(xenc, pWenc, pUW, ebih, ebhh, Ubias,
                                      hstate, encB, uoB);
  k_dec <<<NB / 4, 512, 0, stream>>>(xdec, xenc, pWdec, pWl, dbih, dbhh,
                                     Wlb, Vw, Vb, how, hob, hstate,
                                     encB, uoB, (float*)d_out);
}

// Round 7
// 1099.211 us; speedup vs baseline: 1.4751x; 1.4751x over previous
//
#include <hip/hip_runtime.h>
#include <stdint.h>

typedef unsigned int u32;
typedef unsigned short u16;
typedef _Float16 f16;
typedef _Float16 f16x8 __attribute__((ext_vector_type(8)));
typedef _Float16 f16x4 __attribute__((ext_vector_type(4)));
typedef _Float16 f16x2 __attribute__((ext_vector_type(2)));
typedef float f32x4 __attribute__((ext_vector_type(4)));

constexpr int NB = 4096;   // batch
constexpr int NT = 56;     // encoder steps
constexpr int NS = 28;     // decoder steps
constexpr int NH = 126;    // hidden
constexpr int NHP = 128;
constexpr float LOG2E = 1.4426950408889634f;

// uoL row geometry: 136 elems (%32 words = 4 -> per-t bank rotation)
constexpr int LROW = 136;
constexpr int LB   = NT * LROW + 8;   // 7624

// encT (j-major enc for p3): [b][jp 0..63][t 0..55] f16x2
constexpr int TJP = 120;    // f16 per jp row (56 t * 2 + pad)
constexpr int TB  = 7712;   // f16 per batch (64*120 + pad)

// workspace offsets (bytes)
constexpr size_t OFF_H    = 0;                    // f32[4096*128] h state (pads 0)
constexpr size_t OFF_ENC  = 2097152;              // f16[4096*56*128] enc_out [b][t][h]
constexpr size_t OFF_UO   = OFF_ENC + 58720256;   // f16[4096*56*128] EU=e^(2*Uo) [b][t][h]
constexpr size_t OFF_WENC = OFF_UO + 58720256;    // f16[384*160]  enc gates [x20+pad|h128]
constexpr size_t OFF_WDEC = OFF_WENC + 122880;    // f16[384*288]  dec gates [head16+pad|attn128|h128]
constexpr size_t OFF_WL   = OFF_WDEC + 221184;    // f16[128*128]  Wl
constexpr size_t OFF_UW   = OFF_WL + 32768;       // f16[128*128]  U_W

__device__ __forceinline__ float fexp2(float x){ return __builtin_amdgcn_exp2f(x); }
__device__ __forceinline__ float frcp (float x){ return __builtin_amdgcn_rcpf(x); }
__device__ __forceinline__ float sigm (float x){ return frcp(1.f + fexp2(-LOG2E * x)); }
__device__ __forceinline__ float ftanh(float x){ return 1.f - 2.f * frcp(1.f + fexp2(2.f * LOG2E * x)); }

// ---------------- weight repack ----------------
__global__ void k_prep(const float* __restrict__ eWih, const float* __restrict__ eWhh,
                       const float* __restrict__ dWih, const float* __restrict__ dWhh,
                       const float* __restrict__ UW,   const float* __restrict__ Wl,
                       char* __restrict__ ws)
{
  f16* wenc = (f16*)(ws + OFF_WENC);
  f16* wdec = (f16*)(ws + OFF_WDEC);
  f16* wl   = (f16*)(ws + OFF_WL);
  f16* uw   = (f16*)(ws + OFF_UW);
  const int nE = 384 * 160, nD = 384 * 288, nW = 128 * 128;
  const int total = nE + nD + nW + nW;
  for (int i = blockIdx.x * 256 + threadIdx.x; i < total; i += gridDim.x * 256) {
    int idx = i;
    if (idx < nE) {
      const int r = idx / 160, c = idx % 160;
      float v = 0.f;
      if (r < 378) {
        if (c < 20) v = eWih[r * 20 + c];
        else if (c >= 32 && c < 158) v = eWhh[r * 126 + (c - 32)];
      }
      wenc[idx] = (f16)v; continue;
    }
    idx -= nE;
    if (idx < nD) {
      const int r = idx / 288, c = idx % 288;
      float v = 0.f;
      if (r < 378) {
        if (c < 16) v = dWih[r * 142 + c];
        else if (c >= 32 && c < 158) v = dWih[r * 142 + 16 + (c - 32)];
        else if (c >= 160 && c < 286) v = dWhh[r * 126 + (c - 160)];
      }
      wdec[idx] = (f16)v; continue;
    }
    idx -= nD;
    if (idx < nW) {
      const int r = idx >> 7, c = idx & 127;
      wl[idx] = (f16)((r < 126 && c < 126) ? Wl[r * 126 + c] : 0.f);
      continue;
    }
    idx -= nW;
    { const int r = idx >> 7, c = idx & 127;
      uw[idx] = (f16)((r < 126 && c < 126) ? UW[r * 126 + c] : 0.f); }
  }
}

// ---------------- init MLP ----------------
__global__ __launch_bounds__(256) void k_mlp(
    const float* __restrict__ ann, const float* __restrict__ W1, const float* __restrict__ b1,
    const float* __restrict__ W2, const float* __restrict__ b2, float* __restrict__ hstate)
{
  __shared__ float anns[32][33];
  __shared__ float t1s[32][101];
  const int tid = threadIdx.x;
  const int b0 = blockIdx.x * 32;
  for (int i = tid; i < 32 * 30; i += 256)
    anns[i / 30][i % 30] = ann[(b0 + i / 30) * 30 + (i % 30)];
  __syncthreads();
  const int b = tid & 31, rg = tid >> 5;
  for (int m = rg; m < 96; m += 8) {
    float a = b1[m];
    for (int k = 0; k < 30; ++k) a += W1[m * 30 + k] * anns[b][k];
    t1s[b][m] = fmaxf(a, 0.f);
  }
  __syncthreads();
  for (int j = rg; j < NHP; j += 8) {
    float a = 0.f;
    if (j < NH) {
      a = b2[j];
      for (int k = 0; k < 96; ++k) a += W2[j * 96 + k] * t1s[b][k];
    }
    hstate[(b0 + b) * NHP + j] = a;
  }
}

// ---------------- encoder: MFMA, reg-resident weights, M=16, h double-buffered ----------------
__global__ __launch_bounds__(512) void k_enc(
    const float* __restrict__ xenc, const f16* __restrict__ Wenc,
    const f16* __restrict__ Uw,
    const float* __restrict__ bih, const float* __restrict__ bhh,
    const float* __restrict__ Ub,
    float* __restrict__ hstate, f16* __restrict__ encO, u16* __restrict__ uoO)
{
  __shared__ f16 av[16][296];   // [b][ x20+pad12 | h_p0 128 | h_p1 128 | pad ]
  const int tid = threadIdx.x;
  const int wid = tid >> 6, l = tid & 63, quad = l >> 4, col = l & 15;
  const int b0 = blockIdx.x * 16;
  const int jb = wid * 16, j = jb + col;
  const bool valid = j < NH;
  const int jc = valid ? j : NH - 1;

  const float br  = bih[jc]        + bhh[jc];
  const float bz  = bih[NH + jc]   + bhh[NH + jc];
  const float bnx = bih[2*NH + jc];
  const float bnh = bhh[2*NH + jc];
  const float ub  = Ub[jc];

  f16x8 rB[5], zB[5], nxB, nhB[4], uB[4];
  {
    const int ko = quad * 8, rr = jb + col;
#pragma unroll
    for (int kt = 0; kt < 5; ++kt) {
      rB[kt] = *(const f16x8*)&Wenc[rr * 160 + kt * 32 + ko];
      zB[kt] = *(const f16x8*)&Wenc[(NH + rr) * 160 + kt * 32 + ko];
    }
    nxB = *(const f16x8*)&Wenc[(2*NH + rr) * 160 + ko];
#pragma unroll
    for (int kt = 0; kt < 4; ++kt) {
      nhB[kt] = *(const f16x8*)&Wenc[(2*NH + rr) * 160 + 32 + kt * 32 + ko];
      uB[kt]  = *(const f16x8*)&Uw[rr * 128 + kt * 32 + ko];
    }
  }

  {
    const int bb = tid >> 5, c4 = (tid & 31) * 4;
    const float4 hv = *(const float4*)&hstate[(b0 + bb) * NHP + c4];
    av[bb][32 + c4]     = (f16)hv.x; av[bb][32 + c4 + 1] = (f16)hv.y;
    av[bb][32 + c4 + 2] = (f16)hv.z; av[bb][32 + c4 + 3] = (f16)hv.w;
  }
  if (tid < 192) { const int bb = tid / 12, p = tid % 12; av[bb][20 + p] = (f16)0.f; }
  __syncthreads();

  const int m = col, ko = quad * 8;
  for (int t = 0; t < NT; ++t) {
    const int hp = 32 + (t & 1) * 128, hq = 32 + ((t + 1) & 1) * 128;
    if (tid < 320) {
      const int bb = tid / 20, e = tid % 20;
      av[bb][e] = (f16)xenc[((size_t)t * NB + b0 + bb) * 20 + e];
    }
    __syncthreads();                       // B1
    f16x8 A[5];
    A[0] = *(const f16x8*)&av[m][ko];
#pragma unroll
    for (int kt = 1; kt < 5; ++kt) A[kt] = *(const f16x8*)&av[m][hp + (kt - 1) * 32 + ko];

    f32x4 Cr = {br, br, br, br}, Cz = {bz, bz, bz, bz};
    f32x4 Cnx = {bnx, bnx, bnx, bnx}, Cnh = {bnh, bnh, bnh, bnh};
#pragma unroll
    for (int kt = 0; kt < 5; ++kt) {
      Cr = __builtin_amdgcn_mfma_f32_16x16x32_f16(A[kt], rB[kt], Cr, 0, 0, 0);
      Cz = __builtin_amdgcn_mfma_f32_16x16x32_f16(A[kt], zB[kt], Cz, 0, 0, 0);
    }
    Cnx = __builtin_amdgcn_mfma_f32_16x16x32_f16(A[0], nxB, Cnx, 0, 0, 0);
#pragma unroll
    for (int kt = 0; kt < 4; ++kt)
      Cnh = __builtin_amdgcn_mfma_f32_16x16x32_f16(A[kt + 1], nhB[kt], Cnh, 0, 0, 0);

    float hv4[4];
#pragma unroll
    for (int c = 0; c < 4; ++c) {
      const int bb = quad * 4 + c;
      const float hold = (float)av[bb][hp + j];
      const float r = sigm(Cr[c]), z = sigm(Cz[c]);
      const float n = ftanh(Cnx[c] + r * Cnh[c]);
      hv4[c] = (1.f - z) * n + z * hold;
    }
#pragma unroll
    for (int c = 0; c < 4; ++c) {
      const int bb = quad * 4 + c;
      const f16 hs = valid ? (f16)hv4[c] : (f16)0.f;
      av[bb][hq + j] = hs;
      encO[((size_t)(b0 + bb) * NT + t) * 128 + j] = hs;
    }
    if (t == NT - 1 && valid) {
#pragma unroll
      for (int c = 0; c < 4; ++c)
        hstate[(b0 + quad * 4 + c) * NHP + j] = hv4[c];
    }
    __syncthreads();                       // B2

    f16x8 Ah[4];
#pragma unroll
    for (int kt = 0; kt < 4; ++kt) Ah[kt] = *(const f16x8*)&av[m][hq + kt * 32 + ko];
    f32x4 Cu = {ub, ub, ub, ub};
#pragma unroll
    for (int kt = 0; kt < 4; ++kt)
      Cu = __builtin_amdgcn_mfma_f32_16x16x32_f16(Ah[kt], uB[kt], Cu, 0, 0, 0);
#pragma unroll
    for (int c = 0; c < 4; ++c) {
      union { f16 h; u16 u; } cv;
      cv.h = (f16)fexp2(2.f * LOG2E * Cu[c]);           // EU = e^(2*Uo), f16
      uoO[((size_t)(b0 + quad * 4 + c) * NT + t) * 128 + j] = valid ? cv.u : (u16)0;
    }
  }
}

// ---------------- decoder: 1024 threads, 16 waves = 8 j-blocks x 2 K-halves ----------------
// kh=0 waves hold x/attn-part gate weights (K-tiles 0..4), kh=1 waves hold h-part
// (K-tiles 5..8) + Wl: 64 VGPR of weights/wave -> 4 waves/SIMD at <=128 VGPR, no spill.
// Gate partials exchanged via LDS (pxr/pxz/pxn); epilogue on kh=1. 5 barriers/step.
__global__ __launch_bounds__(1024, 4) void k_dec(
    const float* __restrict__ xdec, const float* __restrict__ xenc,
    const f16* __restrict__ Wdec, const f16* __restrict__ WlW,
    const float* __restrict__ bih, const float* __restrict__ bhh,
    const float* __restrict__ Wlb, const float* __restrict__ Vw,
    const float* __restrict__ Vb, const float* __restrict__ how,
    const float* __restrict__ hob, const float* __restrict__ hstate,
    const f16* __restrict__ encO, const u16* __restrict__ uoO,
    float* __restrict__ out)
{
  __shared__ __align__(16) u16 uoL[4 * LB];      // EU f16 bits, 61.0 KB, t-major
  __shared__ __align__(16) f16 encT[4 * TB];     // enc f16, 61.7 KB, j-major
  __shared__ __align__(16) f16 av[5][424];       // [b][head16+pad16|attn128|h_p0|h_p1|pad]; row4=0
  __shared__ float EWS[4][132];                  // e^(2*Wh)
  __shared__ float scS[4][60];                   // exp(score)
  __shared__ float pxr[4][132], pxz[4][132], pxn[4][132];  // gi partials (x/attn half)
  __shared__ float n2vL[128];                    // -2*v
  __shared__ __align__(16) f16 hows16[128];
  const int tid = threadIdx.x;
  const int wid = tid >> 6, l = tid & 63, quad = l >> 4, col = l & 15;
  const int kh = wid >> 3, jw = wid & 7;
  const int b0 = blockIdx.x * 4;
  const int jb = jw * 16, j = jb + col;
  const bool valid = j < NH;
  const int jc = valid ? j : NH - 1;

  const float br  = bih[jc]        + bhh[jc];
  const float bz  = bih[NH + jc]   + bhh[NH + jc];
  const float bnx = bih[2*NH + jc];
  const float bnh = bhh[2*NH + jc];
  const float wb  = Wlb[jc];
  const float vb0 = Vb[0], hob0 = hob[0];

  // flat weight pool, 16 frags = 64 VGPR both halves
  // kh=0: W[0..4]=rB K0-4, W[5..9]=zB K0-4, W[10..14]=nxB K0-4, W[15]=0
  // kh=1: W[0..3]=rB K5-8, W[4..7]=zB K5-8, W[8..11]=nhB, W[12..15]=wlB
  f16x8 W[16];
  {
    const int ko = quad * 8, rr = jb + col;
    if (kh == 0) {
#pragma unroll
      for (int kt = 0; kt < 5; ++kt) {
        W[kt]      = *(const f16x8*)&Wdec[rr * 288 + kt * 32 + ko];
        W[5 + kt]  = *(const f16x8*)&Wdec[(NH + rr) * 288 + kt * 32 + ko];
        W[10 + kt] = *(const f16x8*)&Wdec[(2*NH + rr) * 288 + kt * 32 + ko];
      }
      W[15] = (f16x8){};
    } else {
#pragma unroll
      for (int kt = 0; kt < 4; ++kt) {
        W[kt]      = *(const f16x8*)&Wdec[rr * 288 + 160 + kt * 32 + ko];
        W[4 + kt]  = *(const f16x8*)&Wdec[(NH + rr) * 288 + 160 + kt * 32 + ko];
        W[8 + kt]  = *(const f16x8*)&Wdec[(2*NH + rr) * 288 + 160 + kt * 32 + ko];
        W[12 + kt] = *(const f16x8*)&WlW[rr * 128 + kt * 32 + ko];
      }
    }
  }

  const int g = tid >> 3, sub = tid & 7;
  float svsum = 0.f;
#pragma unroll
  for (int i = 0; i < 16; ++i) {
    const int jj = sub * 16 + i;
    svsum += (jj < NH) ? Vw[jj] : 0.f;
  }
  if (tid < 128) n2vL[tid] = -2.f * ((tid < NH) ? Vw[tid] : 0.f);
  if (tid >= 256 && tid < 384) {
    const int q = tid - 256; hows16[q] = (f16)((q < NH) ? how[q] : 0.f);
  }
  for (int i = tid; i < 5 * 424; i += 1024) av[i / 424][i % 424] = (f16)0.f;
  if (tid < 24) EWS[tid / 6][126 + tid % 6] = 0.f;   // pad cols stay 0 (avoid NaN)
  {
    const size_t gb = (size_t)b0 * NT * 128;
    for (int i = tid; i < 4 * NT * 16; i += 1024) {
      const int ch = i & 15, btr = i >> 4;
      const int bb = btr / NT, tt = btr % NT;
      const size_t src = gb + (size_t)btr * 128 + ch * 8;
      *(f16x8*)&uoL[bb * LB + tt * LROW + ch * 8] = *(const f16x8*)&uoO[src];
      const f16x8 ev = *(const f16x8*)&encO[src];
#pragma unroll
      for (int k2 = 0; k2 < 4; ++k2) {   // transpose to j-major: jp = ch*4+k2
        f16x2 pr; pr[0] = ev[2 * k2]; pr[1] = ev[2 * k2 + 1];
        *(f16x2*)&encT[bb * TB + (ch * 4 + k2) * TJP + tt * 2] = pr;
      }
    }
  }
  __syncthreads();
  if (tid < 128) {   // h0 rows 0..3 into parity-0 [160..288)
    const int bb = tid >> 5, c4 = (tid & 31) * 4;
    const float4 hv = *(const float4*)&hstate[(b0 + bb) * NHP + c4];
    av[bb][160 + c4]     = (f16)hv.x; av[bb][160 + c4 + 1] = (f16)hv.y;
    av[bb][160 + c4 + 2] = (f16)hv.z; av[bb][160 + c4 + 3] = (f16)hv.w;
  }
  if (tid < 4) av[tid][0] = (f16)xenc[((size_t)(NT - 1) * NB + b0 + tid) * 20];  // gt0
  __syncthreads();

  const int m = col, ko = quad * 8;
  // batch b feeds A-row 4b; rows with m%4!=0 read the zero row 4
  const int arow = ((m & 3) == 0) ? (m >> 2) : 4;
  // p3 map: (batch, t-quarter, j-pair)
  const int pb = tid & 3, pth = (tid >> 2) & 3, pjp = tid >> 4;

  for (int s = 0; s < NS; ++s) {
    const int hp = 160 + (s & 1) * 128, hq = 160 + ((s + 1) & 1) * 128;

    // p1 (kh=1 only): Wh -> EW (MFMA, h-part weights); merged p5 on wid==8.
    if (kh == 1) {
      f16x8 Ah[4];
#pragma unroll
      for (int kt = 0; kt < 4; ++kt) Ah[kt] = *(const f16x8*)&av[arow][hp + kt * 32 + ko];
      f32x4 Cw = {wb, wb, wb, wb};
#pragma unroll
      for (int kt = 0; kt < 4; ++kt)
        Cw = __builtin_amdgcn_mfma_f32_16x16x32_f16(Ah[kt], W[12 + kt], Cw, 0, 0, 0);
      if (valid) EWS[quad][j] = fexp2(2.f * LOG2E * Cw[0]);
      if (wid == 8 && s > 0) {           // p5 for previous step: hp(s) == hq(s-1)
        f16x8 hB[4];
        const f16x8 zz = {};
#pragma unroll
        for (int kt = 0; kt < 4; ++kt)
          hB[kt] = (col == 0) ? *(const f16x8*)&hows16[kt * 32 + ko] : zz;
        f32x4 Co = {0.f, 0.f, 0.f, 0.f};
#pragma unroll
        for (int kt = 0; kt < 4; ++kt)
          Co = __builtin_amdgcn_mfma_f32_16x16x32_f16(Ah[kt], hB[kt], Co, 0, 0, 0);
        if (col == 0) {
          const float o = Co[0] + hob0;
          out[(size_t)(s - 1) * NB + b0 + quad] = o;
          av[quad][0] = (f16)o;          // prev feedback; ordered by B1..B3 before p4
        }
      }
    }
    if (tid < 60) { const int bb = tid / 15, e = tid % 15;
      av[bb][1 + e] = (f16)xdec[((size_t)s * NB + b0 + bb) * 15 + e]; }
    __syncthreads();  // B1

    // p2: scores; 128 groups = 4b x 32 t-base, 2 rounds into rs[2]; interleaved tree.
    {
      const int sbb = g & 3, tb = g >> 2;
      float ew[16], nv[16];
#pragma unroll
      for (int i = 0; i < 4; ++i) {
        *(float4*)&ew[i * 4] = *(const float4*)&EWS[sbb][sub * 16 + i * 4];
        *(float4*)&nv[i * 4] = *(const float4*)&n2vL[sub * 16 + i * 4];
      }
      const u16* up0 = &uoL[sbb * LB + sub * 16];
      uint4 q0 = *(const uint4*)&up0[tb * LROW];
      uint4 q1 = *(const uint4*)&up0[tb * LROW + 8];
      float rs[2];
#pragma unroll
      for (int rd = 0; rd < 2; ++rd) {
        const u32 wsv[8] = {q0.x, q0.y, q0.z, q0.w, q1.x, q1.y, q1.z, q1.w};
        if (rd == 0) {
          const int tn = (32 + tb < NT) ? (32 + tb) : (NT - 1);
          q0 = *(const uint4*)&up0[tn * LROW];
          q1 = *(const uint4*)&up0[tn * LROW + 8];
        }
        float ac0 = 0.f, ac1 = 0.f, ac2 = 0.f, ac3 = 0.f;
#pragma unroll
        for (int k = 0; k < 8; k += 2) {
          union { u32 i; f16x2 h; } ua, ub2;
          ua.i = wsv[k]; ub2.i = wsv[k + 1];
          const float p0 = fmaf((float)ua.h[0],  ew[2 * k],     1.f);
          const float p1 = fmaf((float)ua.h[1],  ew[2 * k + 1], 1.f);
          const float p2 = fmaf((float)ub2.h[0], ew[2 * k + 2], 1.f);
          const float p3 = fmaf((float)ub2.h[1], ew[2 * k + 3], 1.f);
          ac0 = fmaf(nv[2 * k],     frcp(p0), ac0);
          ac1 = fmaf(nv[2 * k + 1], frcp(p1), ac1);
          ac2 = fmaf(nv[2 * k + 2], frcp(p2), ac2);
          ac3 = fmaf(nv[2 * k + 3], frcp(p3), ac3);
        }
        rs[rd] = svsum + (ac0 + ac1) + (ac2 + ac3);
      }
      rs[0] += __shfl_xor(rs[0], 1, 64);
      rs[1] += __shfl_xor(rs[1], 1, 64);
      rs[0] += __shfl_xor(rs[0], 2, 64);
      rs[1] += __shfl_xor(rs[1], 2, 64);
      rs[0] += __shfl_xor(rs[0], 4, 64);
      rs[1] += __shfl_xor(rs[1], 4, 64);
      if (sub == 0) {
        scS[sbb][tb] = fexp2(LOG2E * (rs[0] + vb0));
        if (32 + tb < NT) scS[sbb][32 + tb] = fexp2(LOG2E * (rs[1] + vb0));
      }
    }
    __syncthreads();  // B2

    // p3: softmax + attn; thread = (batch, t-quarter 16/16/16/8, j-pair)
    {
      const int j0 = pjp * 2;
      const f16* er = &encT[pb * TB + pjp * TJP + pth * 32];
      const float* scp = &scS[pb][pth * 16];
      const int nit = (pth == 3) ? 2 : 4;
      float Za = 0.f, Zb = 0.f;
      float a0a = 0.f, a0b = 0.f, a1a = 0.f, a1b = 0.f;
#pragma unroll
      for (int it = 0; it < 4; ++it) {
        if (it < nit) {
          const f16x8 ev = *(const f16x8*)&er[it * 8];
          const float4 sc = *(const float4*)&scp[it * 4];
          Za += sc.x + sc.z; Zb += sc.y + sc.w;
          a0a = fmaf(sc.x, (float)ev[0], a0a);
          a1a = fmaf(sc.x, (float)ev[1], a1a);
          a0b = fmaf(sc.y, (float)ev[2], a0b);
          a1b = fmaf(sc.y, (float)ev[3], a1b);
          a0a = fmaf(sc.z, (float)ev[4], a0a);
          a1a = fmaf(sc.z, (float)ev[5], a1a);
          a0b = fmaf(sc.w, (float)ev[6], a0b);
          a1b = fmaf(sc.w, (float)ev[7], a1b);
        }
      }
      float Z = Za + Zb, a0 = a0a + a0b, a1 = a1a + a1b;
      a0 += __shfl_xor(a0, 4, 64);
      a1 += __shfl_xor(a1, 4, 64);
      Z  += __shfl_xor(Z, 4, 64);
      a0 += __shfl_xor(a0, 8, 64);
      a1 += __shfl_xor(a1, 8, 64);
      Z  += __shfl_xor(Z, 8, 64);
      if (pth == 0) {
        const float inv = frcp(Z);
        f16x2 st; st[0] = (f16)(a0 * inv); st[1] = (f16)(a1 * inv);
        *(f16x2*)&av[pb][32 + j0] = st;
      }
    }
    __syncthreads();  // B3

    // p4: gate GEMM split across kh halves; partials via LDS; epilogue on kh=1.
    if (kh == 0) {
      f16x8 A[5];
#pragma unroll
      for (int kt = 0; kt < 5; ++kt) A[kt] = *(const f16x8*)&av[arow][kt * 32 + ko];
      f32x4 Cr = {br, br, br, br}, Cz = {bz, bz, bz, bz};
      f32x4 Cnx = {bnx, bnx, bnx, bnx};
#pragma unroll
      for (int kt = 0; kt < 5; ++kt) {
        Cr  = __builtin_amdgcn_mfma_f32_16x16x32_f16(A[kt], W[kt],      Cr,  0, 0, 0);
        Cz  = __builtin_amdgcn_mfma_f32_16x16x32_f16(A[kt], W[5 + kt],  Cz,  0, 0, 0);
        Cnx = __builtin_amdgcn_mfma_f32_16x16x32_f16(A[kt], W[10 + kt], Cnx, 0, 0, 0);
      }
      pxr[quad][j] = Cr[0];
      pxz[quad][j] = Cz[0];
      pxn[quad][j] = Cnx[0];
      __syncthreads();  // B4a
    } else {
      f16x8 Ah[4];
#pragma unroll
      for (int kt = 0; kt < 4; ++kt) Ah[kt] = *(const f16x8*)&av[arow][hp + kt * 32 + ko];
      f32x4 Cr = {0.f, 0.f, 0.f, 0.f}, Cz = {0.f, 0.f, 0.f, 0.f};
      f32x4 Cnh = {bnh, bnh, bnh, bnh};
#pragma unroll
      for (int kt = 0; kt < 4; ++kt) {
        Cr  = __builtin_amdgcn_mfma_f32_16x16x32_f16(Ah[kt], W[kt],     Cr,  0, 0, 0);
        Cz  = __builtin_amdgcn_mfma_f32_16x16x32_f16(Ah[kt], W[4 + kt], Cz,  0, 0, 0);
        Cnh = __builtin_amdgcn_mfma_f32_16x16x32_f16(Ah[kt], W[8 + kt], Cnh, 0, 0, 0);
      }
      __syncthreads();  // B4a
      const float hold = (float)av[quad][hp + j];
      const float r = sigm(pxr[quad][j] + Cr[0]);
      const float z = sigm(pxz[quad][j] + Cz[0]);
      const float n = ftanh(pxn[quad][j] + r * Cnh[0]);
      const float h2 = (1.f - z) * n + z * hold;
      if (valid) av[quad][hq + j] = (f16)h2;
    }
    __syncthreads();  // B4b
  }

  // epilogue p5 for s = NS-1 (B4b of last iter orders p4 writes before these reads)
  if (wid == 8) {
    const int hql = 160 + (NS & 1) * 128;
    f16x8 Ah2[4], hB[4];
    const f16x8 zz = {};
#pragma unroll
    for (int kt = 0; kt < 4; ++kt) {
      Ah2[kt] = *(const f16x8*)&av[arow][hql + kt * 32 + ko];
      hB[kt] = (col == 0) ? *(const f16x8*)&hows16[kt * 32 + ko] : zz;
    }
    f32x4 Co = {0.f, 0.f, 0.f, 0.f};
#pragma unroll
    for (int kt = 0; kt < 4; ++kt)
      Co = __builtin_amdgcn_mfma_f32_16x16x32_f16(Ah2[kt], hB[kt], Co, 0, 0, 0);
    if (col == 0) out[(size_t)(NS - 1) * NB + b0 + quad] = Co[0] + hob0;
  }
}

extern "C" void kernel_launch(void* const* d_in, const int* in_sizes, int n_in,
                              void* d_out, int out_size, void* d_ws, size_t ws_size,
                              hipStream_t stream)
{
  const float* ann   = (const float*)d_in[0];
  const float* xenc  = (const float*)d_in[1];
  const float* xdec  = (const float*)d_in[2];
  const float* W1    = (const float*)d_in[3];
  const float* b1    = (const float*)d_in[4];
  const float* W2    = (const float*)d_in[5];
  const float* b2    = (const float*)d_in[6];
  const float* eWih  = (const float*)d_in[7];
  const float* eWhh  = (const float*)d_in[8];
  const float* ebih  = (const float*)d_in[9];
  const float* ebhh  = (const float*)d_in[10];
  const float* dWih  = (const float*)d_in[11];
  const float* dWhh  = (const float*)d_in[12];
  const float* dbih  = (const float*)d_in[13];
  const float* dbhh  = (const float*)d_in[14];
  const float* UW    = (const float*)d_in[15];
  const float* Ubias = (const float*)d_in[16];
  const float* Wl    = (const float*)d_in[17];
  const float* Wlb   = (const float*)d_in[18];
  const float* Vw    = (const float*)d_in[19];
  const float* Vb    = (const float*)d_in[20];
  const float* how   = (const float*)d_in[21];
  const float* hob   = (const float*)d_in[22];

  char* ws = (char*)d_ws;
  float* hstate = (float*)(ws + OFF_H);
  f16*   encB   = (f16*)(ws + OFF_ENC);
  u16*   uoB    = (u16*)(ws + OFF_UO);
  const f16* pWenc = (const f16*)(ws + OFF_WENC);
  const f16* pWdec = (const f16*)(ws + OFF_WDEC);
  const f16* pWl   = (const f16*)(ws + OFF_WL);
  const f16* pUW   = (const f16*)(ws + OFF_UW);

  k_prep<<<200, 256, 0, stream>>>(eWih, eWhh, dWih, dWhh, UW, Wl, ws);
  k_mlp <<<128, 256, 0, stream>>>(ann, W1, b1, W2, b2, hstate);
  k_enc <<<NB / 16, 512, 0, stream>>>(xenc, pWenc, pUW, ebih, ebhh, Ubias,
                                      hstate, encB, uoB);
  k_dec <<<NB / 4, 1024, 0, stream>>>(xdec, xenc, pWdec, pWl, dbih, dbhh,
                                      Wlb, Vw, Vb, how, hob, hstate,
                                      encB, uoB, (float*)d_out);
}

// Round 8
// 582.256 us; speedup vs baseline: 2.7847x; 1.8878x over previous
//
#include <hip/hip_runtime.h>
#include <stdint.h>

typedef unsigned int u32;
typedef unsigned short u16;
typedef _Float16 f16;
typedef _Float16 f16x8 __attribute__((ext_vector_type(8)));
typedef _Float16 f16x4 __attribute__((ext_vector_type(4)));
typedef _Float16 f16x2 __attribute__((ext_vector_type(2)));
typedef float f32x4 __attribute__((ext_vector_type(4)));

constexpr int NB = 4096;   // batch
constexpr int NT = 56;     // encoder steps
constexpr int NS = 28;     // decoder steps
constexpr int NH = 126;    // hidden
constexpr int NHP = 128;
constexpr float LOG2E = 1.4426950408889634f;

// decoder LDS row geometry: uoL row 136 elems (%32 words = 4 -> per-t bank rotation)
constexpr int LROW = 136;
constexpr int LB   = NT * LROW + 8;   // 7624

// encT (j-major enc for p3): [b][jp 0..63][t 0..55] f16x2
constexpr int TJP = 120;    // f16 per jp row (56 t * 2 + pad)
constexpr int TB  = 7712;   // f16 per batch (64*120 + pad)

// encoder av row: [ x_p0 20 | pad12 | h_p0 128 | h_p1 128 | pad16 | x_p1 20 | pad12 ]
constexpr int EROW = 344;   // 688 B/row; 172 words %32 = 12 -> conflict-free frag reads

// workspace offsets (bytes)
constexpr size_t OFF_H    = 0;                    // f32[4096*128] h state (pads 0)
constexpr size_t OFF_ENC  = 2097152;              // f16[4096*56*128] enc_out [b][t][h]
constexpr size_t OFF_UO   = OFF_ENC + 58720256;   // f16[4096*56*128] EU=e^(2*Uo) [b][t][h]
constexpr size_t OFF_WENC = OFF_UO + 58720256;    // f16[384*160]  enc gates [x20+pad|h128]
constexpr size_t OFF_WDEC = OFF_WENC + 122880;    // f16[384*288]  dec gates [head16+pad|attn128|h128]
constexpr size_t OFF_WL   = OFF_WDEC + 221184;    // f16[128*128]  Wl
constexpr size_t OFF_UW   = OFF_WL + 32768;       // f16[128*128]  U_W

__device__ __forceinline__ float fexp2(float x){ return __builtin_amdgcn_exp2f(x); }
__device__ __forceinline__ float frcp (float x){ return __builtin_amdgcn_rcpf(x); }
__device__ __forceinline__ float sigm (float x){ return frcp(1.f + fexp2(-LOG2E * x)); }
__device__ __forceinline__ float ftanh(float x){ return 1.f - 2.f * frcp(1.f + fexp2(2.f * LOG2E * x)); }

// ---------------- weight repack ----------------
__global__ void k_prep(const float* __restrict__ eWih, const float* __restrict__ eWhh,
                       const float* __restrict__ dWih, const float* __restrict__ dWhh,
                       const float* __restrict__ UW,   const float* __restrict__ Wl,
                       char* __restrict__ ws)
{
  f16* wenc = (f16*)(ws + OFF_WENC);
  f16* wdec = (f16*)(ws + OFF_WDEC);
  f16* wl   = (f16*)(ws + OFF_WL);
  f16* uw   = (f16*)(ws + OFF_UW);
  const int nE = 384 * 160, nD = 384 * 288, nW = 128 * 128;
  const int total = nE + nD + nW + nW;
  for (int i = blockIdx.x * 256 + threadIdx.x; i < total; i += gridDim.x * 256) {
    int idx = i;
    if (idx < nE) {
      const int r = idx / 160, c = idx % 160;
      float v = 0.f;
      if (r < 378) {
        if (c < 20) v = eWih[r * 20 + c];
        else if (c >= 32 && c < 158) v = eWhh[r * 126 + (c - 32)];
      }
      wenc[idx] = (f16)v; continue;
    }
    idx -= nE;
    if (idx < nD) {
      const int r = idx / 288, c = idx % 288;
      float v = 0.f;
      if (r < 378) {
        if (c < 16) v = dWih[r * 142 + c];
        else if (c >= 32 && c < 158) v = dWih[r * 142 + 16 + (c - 32)];
        else if (c >= 160 && c < 286) v = dWhh[r * 126 + (c - 160)];
      }
      wdec[idx] = (f16)v; continue;
    }
    idx -= nD;
    if (idx < nW) {
      const int r = idx >> 7, c = idx & 127;
      wl[idx] = (f16)((r < 126 && c < 126) ? Wl[r * 126 + c] : 0.f);
      continue;
    }
    idx -= nW;
    { const int r = idx >> 7, c = idx & 127;
      uw[idx] = (f16)((r < 126 && c < 126) ? UW[r * 126 + c] : 0.f); }
  }
}

// ---------------- init MLP ----------------
__global__ __launch_bounds__(256) void k_mlp(
    const float* __restrict__ ann, const float* __restrict__ W1, const float* __restrict__ b1,
    const float* __restrict__ W2, const float* __restrict__ b2, float* __restrict__ hstate)
{
  __shared__ float anns[32][33];
  __shared__ float t1s[32][101];
  const int tid = threadIdx.x;
  const int b0 = blockIdx.x * 32;
  for (int i = tid; i < 32 * 30; i += 256)
    anns[i / 30][i % 30] = ann[(b0 + i / 30) * 30 + (i % 30)];
  __syncthreads();
  const int b = tid & 31, rg = tid >> 5;
  for (int m = rg; m < 96; m += 8) {
    float a = b1[m];
    for (int k = 0; k < 30; ++k) a += W1[m * 30 + k] * anns[b][k];
    t1s[b][m] = fmaxf(a, 0.f);
  }
  __syncthreads();
  for (int j = rg; j < NHP; j += 8) {
    float a = 0.f;
    if (j < NH) {
      a = b2[j];
      for (int k = 0; k < 96; ++k) a += W2[j * 96 + k] * t1s[b][k];
    }
    hstate[(b0 + b) * NHP + j] = a;
  }
}

// ---------------- encoder: MFMA, reg-resident weights, M=16, single barrier/step ----------
// Uo(t-1) merged into step t: its A-fragments are the SAME av[m][hp+...] the gates read
// (hp(t) == hq(t-1)), so the Cu MFMAs reuse A[1..4] with zero extra LDS reads, and B2 is
// gone. x is double-buffered (x(t+1) prefetched from global during step t's compute).
__global__ __launch_bounds__(512) void k_enc(
    const float* __restrict__ xenc, const f16* __restrict__ Wenc,
    const f16* __restrict__ Uw,
    const float* __restrict__ bih, const float* __restrict__ bhh,
    const float* __restrict__ Ub,
    float* __restrict__ hstate, f16* __restrict__ encO, u16* __restrict__ uoO)
{
  __shared__ f16 av[16][EROW];
  const int tid = threadIdx.x;
  const int wid = tid >> 6, l = tid & 63, quad = l >> 4, col = l & 15;
  const int b0 = blockIdx.x * 16;
  const int jb = wid * 16, j = jb + col;
  const bool valid = j < NH;
  const int jc = valid ? j : NH - 1;

  const float br  = bih[jc]        + bhh[jc];
  const float bz  = bih[NH + jc]   + bhh[NH + jc];
  const float bnx = bih[2*NH + jc];
  const float bnh = bhh[2*NH + jc];
  const float ub  = Ub[jc];

  f16x8 rB[5], zB[5], nxB, nhB[4], uB[4];
  {
    const int ko = quad * 8, rr = jb + col;
#pragma unroll
    for (int kt = 0; kt < 5; ++kt) {
      rB[kt] = *(const f16x8*)&Wenc[rr * 160 + kt * 32 + ko];
      zB[kt] = *(const f16x8*)&Wenc[(NH + rr) * 160 + kt * 32 + ko];
    }
    nxB = *(const f16x8*)&Wenc[(2*NH + rr) * 160 + ko];
#pragma unroll
    for (int kt = 0; kt < 4; ++kt) {
      nhB[kt] = *(const f16x8*)&Wenc[(2*NH + rr) * 160 + 32 + kt * 32 + ko];
      uB[kt]  = *(const f16x8*)&Uw[rr * 128 + kt * 32 + ko];
    }
  }

  {  // h(0) into parity-0 [32..160)
    const int bb = tid >> 5, c4 = (tid & 31) * 4;
    const float4 hv = *(const float4*)&hstate[(b0 + bb) * NHP + c4];
    av[bb][32 + c4]     = (f16)hv.x; av[bb][32 + c4 + 1] = (f16)hv.y;
    av[bb][32 + c4 + 2] = (f16)hv.z; av[bb][32 + c4 + 3] = (f16)hv.w;
  }
  if (tid < 384) {  // zero x-tails of both parities: [20,32) and [324,336)
    const int bb = tid / 24, p = tid % 24;
    av[bb][(p < 12) ? (20 + p) : (312 + p)] = (f16)0.f;
  }
  const int bb320 = tid / 20, e320 = tid % 20;
  if (tid < 320)   // x(0) into parity-0 [0..20)
    av[bb320][e320] = (f16)xenc[((size_t)0 * NB + b0 + bb320) * 20 + e320];
  __syncthreads();

  const int m = col, ko = quad * 8;
  for (int t = 0; t < NT; ++t) {
    const int hp = 32 + (t & 1) * 128, hq = 32 + ((t + 1) & 1) * 128;
    const int xp = (t & 1) ? 304 : 0,  xq = ((t + 1) & 1) ? 304 : 0;

    // prefetch x(t+1) from global (latency hidden under the MFMAs below)
    float xv = 0.f;
    const bool ldx = (tid < 320) && (t + 1 < NT);
    if (ldx) xv = xenc[((size_t)(t + 1) * NB + b0 + bb320) * 20 + e320];

    f16x8 A[5];
    A[0] = *(const f16x8*)&av[m][xp + ko];
#pragma unroll
    for (int kt = 1; kt < 5; ++kt) A[kt] = *(const f16x8*)&av[m][hp + (kt - 1) * 32 + ko];

    // Uo for step t-1: enc_out(t-1) == h(t) == A[1..4] (free fragment reuse)
    if (t) {
      f32x4 Cu = {ub, ub, ub, ub};
#pragma unroll
      for (int kt = 0; kt < 4; ++kt)
        Cu = __builtin_amdgcn_mfma_f32_16x16x32_f16(A[kt + 1], uB[kt], Cu, 0, 0, 0);
#pragma unroll
      for (int c = 0; c < 4; ++c) {
        union { f16 h; u16 u; } cv;
        cv.h = (f16)fexp2(2.f * LOG2E * Cu[c]);         // EU = e^(2*Uo), f16
        uoO[((size_t)(b0 + quad * 4 + c) * NT + (t - 1)) * 128 + j] = valid ? cv.u : (u16)0;
      }
    }

    f32x4 Cr = {br, br, br, br}, Cz = {bz, bz, bz, bz};
    f32x4 Cnx = {bnx, bnx, bnx, bnx}, Cnh = {bnh, bnh, bnh, bnh};
#pragma unroll
    for (int kt = 0; kt < 5; ++kt) {
      Cr = __builtin_amdgcn_mfma_f32_16x16x32_f16(A[kt], rB[kt], Cr, 0, 0, 0);
      Cz = __builtin_amdgcn_mfma_f32_16x16x32_f16(A[kt], zB[kt], Cz, 0, 0, 0);
    }
    Cnx = __builtin_amdgcn_mfma_f32_16x16x32_f16(A[0], nxB, Cnx, 0, 0, 0);
#pragma unroll
    for (int kt = 0; kt < 4; ++kt)
      Cnh = __builtin_amdgcn_mfma_f32_16x16x32_f16(A[kt + 1], nhB[kt], Cnh, 0, 0, 0);

    float hv4[4];
#pragma unroll
    for (int c = 0; c < 4; ++c) {
      const int bb = quad * 4 + c;
      const float hold = (float)av[bb][hp + j];
      const float r = sigm(Cr[c]), z = sigm(Cz[c]);
      const float n = ftanh(Cnx[c] + r * Cnh[c]);
      hv4[c] = (1.f - z) * n + z * hold;
    }
#pragma unroll
    for (int c = 0; c < 4; ++c) {
      const int bb = quad * 4 + c;
      const f16 hs = valid ? (f16)hv4[c] : (f16)0.f;
      av[bb][hq + j] = hs;
      encO[((size_t)(b0 + bb) * NT + t) * 128 + j] = hs;
    }
    if (t == NT - 1 && valid) {
#pragma unroll
      for (int c = 0; c < 4; ++c)
        hstate[(b0 + quad * 4 + c) * NHP + j] = hv4[c];
    }
    if (ldx) av[bb320][xq + e320] = (f16)xv;
    __syncthreads();                       // single barrier per step
  }

  // Uo for the last step (h(NT) is in parity NT&1 == 0; ordered by the final barrier)
  {
    f16x8 Ah[4];
#pragma unroll
    for (int kt = 0; kt < 4; ++kt) Ah[kt] = *(const f16x8*)&av[m][32 + kt * 32 + ko];
    f32x4 Cu = {ub, ub, ub, ub};
#pragma unroll
    for (int kt = 0; kt < 4; ++kt)
      Cu = __builtin_amdgcn_mfma_f32_16x16x32_f16(Ah[kt], uB[kt], Cu, 0, 0, 0);
#pragma unroll
    for (int c = 0; c < 4; ++c) {
      union { f16 h; u16 u; } cv;
      cv.h = (f16)fexp2(2.f * LOG2E * Cu[c]);
      uoO[((size_t)(b0 + quad * 4 + c) * NT + (NT - 1)) * 128 + j] = valid ? cv.u : (u16)0;
    }
  }
}

// ---------------- decoder: M=4 at A-rows {0,4,8,12}, 512 threads, LDS-resident EU+enc ------
// (R3 structure, best verified: 417 us) p2: 4 rounds into rs[4], one interleaved shuffle
// tree; EU f16 -> unpack folds into v_fma_mix; p5 merged into p1 of next step.
__global__ __launch_bounds__(512, 2) void k_dec(
    const float* __restrict__ xdec, const float* __restrict__ xenc,
    const f16* __restrict__ Wdec, const f16* __restrict__ WlW,
    const float* __restrict__ bih, const float* __restrict__ bhh,
    const float* __restrict__ Wlb, const float* __restrict__ Vw,
    const float* __restrict__ Vb, const float* __restrict__ how,
    const float* __restrict__ hob, const float* __restrict__ hstate,
    const f16* __restrict__ encO, const u16* __restrict__ uoO,
    float* __restrict__ out)
{
  __shared__ __align__(16) u16 uoL[4 * LB];      // EU f16 bits, 61.0 KB, t-major
  __shared__ __align__(16) f16 encT[4 * TB];     // enc f16, 61.7 KB, j-major
  __shared__ __align__(16) f16 av[5][424];       // [b][head16+pad16|attn128|h_p0|h_p1|pad]; row4=0
  __shared__ float EWS[4][132];                  // e^(2*Wh)
  __shared__ float scS[4][60];                   // exp(score)
  __shared__ __align__(16) f16 hows16[128];
  const int tid = threadIdx.x;
  const int wid = tid >> 6, l = tid & 63, quad = l >> 4, col = l & 15;
  const int b0 = blockIdx.x * 4;
  const int jb = wid * 16, j = jb + col;
  const bool valid = j < NH;
  const int jc = valid ? j : NH - 1;

  const float br  = bih[jc]        + bhh[jc];
  const float bz  = bih[NH + jc]   + bhh[NH + jc];
  const float bnx = bih[2*NH + jc];
  const float bnh = bhh[2*NH + jc];
  const float wb  = Wlb[jc];
  const float vb0 = Vb[0], hob0 = hob[0];

  f16x8 rB[9], zB[9], nxB[5], nhB[4], wlB[4];
  {
    const int ko = quad * 8, rr = jb + col;
#pragma unroll
    for (int kt = 0; kt < 9; ++kt) {
      rB[kt] = *(const f16x8*)&Wdec[rr * 288 + kt * 32 + ko];
      zB[kt] = *(const f16x8*)&Wdec[(NH + rr) * 288 + kt * 32 + ko];
    }
#pragma unroll
    for (int kt = 0; kt < 5; ++kt)
      nxB[kt] = *(const f16x8*)&Wdec[(2*NH + rr) * 288 + kt * 32 + ko];
#pragma unroll
    for (int kt = 0; kt < 4; ++kt) {
      nhB[kt] = *(const f16x8*)&Wdec[(2*NH + rr) * 288 + 160 + kt * 32 + ko];
      wlB[kt] = *(const f16x8*)&WlW[rr * 128 + kt * 32 + ko];
    }
  }

  const int g = tid >> 3, sub = tid & 7;
  float n2v[16], svsum = 0.f;
#pragma unroll
  for (int i = 0; i < 16; ++i) {
    const int jj = sub * 16 + i;
    const float v = (jj < NH) ? Vw[jj] : 0.f;
    n2v[i] = -2.f * v;
    svsum += v;
  }
  if (tid >= 256 && tid < 384) {
    const int q = tid - 256; hows16[q] = (f16)((q < NH) ? how[q] : 0.f);
  }
  for (int i = tid; i < 5 * 424; i += 512) av[i / 424][i % 424] = (f16)0.f;
  if (tid < 24) EWS[tid / 6][126 + tid % 6] = 0.f;   // pad cols stay 0 (avoid NaN)
  {
    const size_t gb = (size_t)b0 * NT * 128;
    for (int i = tid; i < 4 * NT * 16; i += 512) {
      const int ch = i & 15, btr = i >> 4;
      const int bb = btr / NT, tt = btr % NT;
      const size_t src = gb + (size_t)btr * 128 + ch * 8;
      *(f16x8*)&uoL[bb * LB + tt * LROW + ch * 8] = *(const f16x8*)&uoO[src];
      const f16x8 ev = *(const f16x8*)&encO[src];
#pragma unroll
      for (int k2 = 0; k2 < 4; ++k2) {   // transpose to j-major: jp = ch*4+k2
        f16x2 pr; pr[0] = ev[2 * k2]; pr[1] = ev[2 * k2 + 1];
        *(f16x2*)&encT[bb * TB + (ch * 4 + k2) * TJP + tt * 2] = pr;
      }
    }
  }
  __syncthreads();
  if (tid < 128) {   // h0 rows 0..3 into parity-0 [160..288)
    const int bb = tid >> 5, c4 = (tid & 31) * 4;
    const float4 hv = *(const float4*)&hstate[(b0 + bb) * NHP + c4];
    av[bb][160 + c4]     = (f16)hv.x; av[bb][160 + c4 + 1] = (f16)hv.y;
    av[bb][160 + c4 + 2] = (f16)hv.z; av[bb][160 + c4 + 3] = (f16)hv.w;
  }
  if (tid < 4) av[tid][0] = (f16)xenc[((size_t)(NT - 1) * NB + b0 + tid) * 20];  // gt0
  __syncthreads();

  const int m = col, ko = quad * 8;
  // batch b feeds A-row 4b; rows with m%4!=0 read the zero row 4
  const int arow = ((m & 3) == 0) ? (m >> 2) : 4;
  const int pb = tid & 3, pth = (tid >> 2) & 1, pjp = tid >> 3;   // p3 map

  for (int s = 0; s < NS; ++s) {
    const int hp = 160 + (s & 1) * 128, hq = 160 + ((s + 1) & 1) * 128;

    // p1: Wh -> EW = e^(2*Wh) (MFMA); merged p5 (out for step s-1) on wave 0; stage dec_x.
    {
      f16x8 Ah[4];
#pragma unroll
      for (int kt = 0; kt < 4; ++kt) Ah[kt] = *(const f16x8*)&av[arow][hp + kt * 32 + ko];
      f32x4 Cw = {wb, wb, wb, wb};
#pragma unroll
      for (int kt = 0; kt < 4; ++kt)
        Cw = __builtin_amdgcn_mfma_f32_16x16x32_f16(Ah[kt], wlB[kt], Cw, 0, 0, 0);
      if (valid) EWS[quad][j] = fexp2(2.f * LOG2E * Cw[0]);
      if (wid == 0 && s > 0) {           // p5 for previous step: hp(s) == hq(s-1)
        f16x8 hB[4];
        const f16x8 zz = {};
#pragma unroll
        for (int kt = 0; kt < 4; ++kt)
          hB[kt] = (col == 0) ? *(const f16x8*)&hows16[kt * 32 + ko] : zz;
        f32x4 Co = {0.f, 0.f, 0.f, 0.f};
#pragma unroll
        for (int kt = 0; kt < 4; ++kt)
          Co = __builtin_amdgcn_mfma_f32_16x16x32_f16(Ah[kt], hB[kt], Co, 0, 0, 0);
        if (col == 0) {
          const float o = Co[0] + hob0;
          out[(size_t)(s - 1) * NB + b0 + quad] = o;
          av[quad][0] = (f16)o;          // prev feedback; ordered by B1..B3 before p4
        }
      }
    }
    if (tid < 60) { const int bb = tid / 15, e = tid % 15;
      av[bb][1 + e] = (f16)xdec[((size_t)s * NB + b0 + bb) * 15 + e]; }
    __syncthreads();  // B1

    // p2: scores via svsum + sum(-2v/(1+EU*EW)); 64 groups = 4b x 16 t-base, 4 rounds
    // accumulated into rs[4]; ONE interleaved reduce tree after all rounds.
    {
      const int sbb = g & 3, tb = g >> 2;
      float ew[16];
#pragma unroll
      for (int i = 0; i < 4; ++i)
        *(float4*)&ew[i * 4] = *(const float4*)&EWS[sbb][sub * 16 + i * 4];
      const u16* up0 = &uoL[sbb * LB + sub * 16];
      uint4 q0 = *(const uint4*)&up0[tb * LROW];
      uint4 q1 = *(const uint4*)&up0[tb * LROW + 8];
      float rs[4];
#pragma unroll
      for (int rd = 0; rd < 4; ++rd) {
        const int t = rd * 16 + tb;
        const u32 wsv[8] = {q0.x, q0.y, q0.z, q0.w, q1.x, q1.y, q1.z, q1.w};
        if (rd < 3) {
          const int tn = (t + 16 < NT) ? (t + 16) : (NT - 1);
          q0 = *(const uint4*)&up0[tn * LROW];
          q1 = *(const uint4*)&up0[tn * LROW + 8];
        }
        float ac0 = 0.f, ac1 = 0.f, ac2 = 0.f, ac3 = 0.f;
#pragma unroll
        for (int k = 0; k < 8; k += 2) {
          union { u32 i; f16x2 h; } ua, ub2;
          ua.i = wsv[k]; ub2.i = wsv[k + 1];
          const float p0 = fmaf((float)ua.h[0],  ew[2 * k],     1.f);
          const float p1 = fmaf((float)ua.h[1],  ew[2 * k + 1], 1.f);
          const float p2 = fmaf((float)ub2.h[0], ew[2 * k + 2], 1.f);
          const float p3 = fmaf((float)ub2.h[1], ew[2 * k + 3], 1.f);
          ac0 = fmaf(n2v[2 * k],     frcp(p0), ac0);
          ac1 = fmaf(n2v[2 * k + 1], frcp(p1), ac1);
          ac2 = fmaf(n2v[2 * k + 2], frcp(p2), ac2);
          ac3 = fmaf(n2v[2 * k + 3], frcp(p3), ac3);
        }
        rs[rd] = svsum + (ac0 + ac1) + (ac2 + ac3);
      }
      rs[0] += __shfl_xor(rs[0], 1, 64);
      rs[1] += __shfl_xor(rs[1], 1, 64);
      rs[2] += __shfl_xor(rs[2], 1, 64);
      rs[3] += __shfl_xor(rs[3], 1, 64);
      rs[0] += __shfl_xor(rs[0], 2, 64);
      rs[1] += __shfl_xor(rs[1], 2, 64);
      rs[2] += __shfl_xor(rs[2], 2, 64);
      rs[3] += __shfl_xor(rs[3], 2, 64);
      rs[0] += __shfl_xor(rs[0], 4, 64);
      rs[1] += __shfl_xor(rs[1], 4, 64);
      rs[2] += __shfl_xor(rs[2], 4, 64);
      rs[3] += __shfl_xor(rs[3], 4, 64);
      if (sub == 0) {
#pragma unroll
        for (int rd = 0; rd < 4; ++rd) {
          const int t = rd * 16 + tb;
          if (t < NT) scS[sbb][t] = fexp2(LOG2E * (rs[rd] + vb0));
        }
      }
    }
    __syncthreads();  // B2

    // p3: softmax + attn; thread = (batch, pth t-half, j-pair); 7 wide b128 reads of encT
    {
      const int j0 = pjp * 2;
      const f16* er = &encT[pb * TB + pjp * TJP + pth * 56];
      const float* scp = &scS[pb][pth * 28];
      float Za = 0.f, Zb = 0.f;
      float a0a = 0.f, a0b = 0.f, a1a = 0.f, a1b = 0.f;
#pragma unroll
      for (int it = 0; it < 7; ++it) {
        const f16x8 ev = *(const f16x8*)&er[it * 8];
        const float4 sc = *(const float4*)&scp[it * 4];
        Za += sc.x; Zb += sc.y; Za += sc.z; Zb += sc.w;
        a0a = fmaf(sc.x, (float)ev[0], a0a);
        a1a = fmaf(sc.x, (float)ev[1], a1a);
        a0b = fmaf(sc.y, (float)ev[2], a0b);
        a1b = fmaf(sc.y, (float)ev[3], a1b);
        a0a = fmaf(sc.z, (float)ev[4], a0a);
        a1a = fmaf(sc.z, (float)ev[5], a1a);
        a0b = fmaf(sc.w, (float)ev[6], a0b);
        a1b = fmaf(sc.w, (float)ev[7], a1b);
      }
      float Z = Za + Zb, a0 = a0a + a0b, a1 = a1a + a1b;
      a0 += __shfl_xor(a0, 4, 64);
      a1 += __shfl_xor(a1, 4, 64);
      Z  += __shfl_xor(Z, 4, 64);
      if (pth == 0) {
        const float inv = frcp(Z);
        f16x2 st; st[0] = (f16)(a0 * inv); st[1] = (f16)(a1 * inv);
        *(f16x2*)&av[pb][32 + j0] = st;
      }
    }
    __syncthreads();  // B3

    // p4: GRU gates (MFMA) + state update; every lane handles one (batch=quad, j) elem
    {
      f16x8 A[9];
#pragma unroll
      for (int kt = 0; kt < 5; ++kt) A[kt] = *(const f16x8*)&av[arow][kt * 32 + ko];
#pragma unroll
      for (int kt = 5; kt < 9; ++kt) A[kt] = *(const f16x8*)&av[arow][hp + (kt - 5) * 32 + ko];
      f32x4 Cr = {br, br, br, br}, Cz = {bz, bz, bz, bz};
      f32x4 Cnx = {bnx, bnx, bnx, bnx}, Cnh = {bnh, bnh, bnh, bnh};
#pragma unroll
      for (int kt = 0; kt < 9; ++kt) {
        Cr = __builtin_amdgcn_mfma_f32_16x16x32_f16(A[kt], rB[kt], Cr, 0, 0, 0);
        Cz = __builtin_amdgcn_mfma_f32_16x16x32_f16(A[kt], zB[kt], Cz, 0, 0, 0);
      }
#pragma unroll
      for (int kt = 0; kt < 5; ++kt)
        Cnx = __builtin_amdgcn_mfma_f32_16x16x32_f16(A[kt], nxB[kt], Cnx, 0, 0, 0);
#pragma unroll
      for (int kt = 0; kt < 4; ++kt)
        Cnh = __builtin_amdgcn_mfma_f32_16x16x32_f16(A[kt + 5], nhB[kt], Cnh, 0, 0, 0);
      {
        const float hold = (float)av[quad][hp + j];
        const float r = sigm(Cr[0]), z = sigm(Cz[0]);
        const float n = ftanh(Cnx[0] + r * Cnh[0]);
        const float h2 = (1.f - z) * n + z * hold;
        if (valid) av[quad][hq + j] = (f16)h2;
      }
    }
    __syncthreads();  // B4
  }

  // epilogue p5 for s = NS-1 (B4 of last iter orders p4 writes before these reads)
  if (wid == 0) {
    const int hql = 160 + (NS & 1) * 128;
    f16x8 Ah2[4], hB[4];
    const f16x8 zz = {};
#pragma unroll
    for (int kt = 0; kt < 4; ++kt) {
      Ah2[kt] = *(const f16x8*)&av[arow][hql + kt * 32 + ko];
      hB[kt] = (col == 0) ? *(const f16x8*)&hows16[kt * 32 + ko] : zz;
    }
    f32x4 Co = {0.f, 0.f, 0.f, 0.f};
#pragma unroll
    for (int kt = 0; kt < 4; ++kt)
      Co = __builtin_amdgcn_mfma_f32_16x16x32_f16(Ah2[kt], hB[kt], Co, 0, 0, 0);
    if (col == 0) out[(size_t)(NS - 1) * NB + b0 + quad] = Co[0] + hob0;
  }
}

extern "C" void kernel_launch(void* const* d_in, const int* in_sizes, int n_in,
                              void* d_out, int out_size, void* d_ws, size_t ws_size,
                              hipStream_t stream)
{
  const float* ann   = (const float*)d_in[0];
  const float* xenc  = (const float*)d_in[1];
  const float* xdec  = (const float*)d_in[2];
  const float* W1    = (const float*)d_in[3];
  const float* b1    = (const float*)d_in[4];
  const float* W2    = (const float*)d_in[5];
  const float* b2    = (const float*)d_in[6];
  const float* eWih  = (const float*)d_in[7];
  const float* eWhh  = (const float*)d_in[8];
  const float* ebih  = (const float*)d_in[9];
  const float* ebhh  = (const float*)d_in[10];
  const float* dWih  = (const float*)d_in[11];
  const float* dWhh  = (const float*)d_in[12];
  const float* dbih  = (const float*)d_in[13];
  const float* dbhh  = (const float*)d_in[14];
  const float* UW    = (const float*)d_in[15];
  const float* Ubias = (const float*)d_in[16];
  const float* Wl    = (const float*)d_in[17];
  const float* Wlb   = (const float*)d_in[18];
  const float* Vw    = (const float*)d_in[19];
  const float* Vb    = (const float*)d_in[20];
  const float* how   = (const float*)d_in[21];
  const float* hob   = (const float*)d_in[22];

  char* ws = (char*)d_ws;
  float* hstate = (float*)(ws + OFF_H);
  f16*   encB   = (f16*)(ws + OFF_ENC);
  u16*   uoB    = (u16*)(ws + OFF_UO);
  const f16* pWenc = (const f16*)(ws + OFF_WENC);
  const f16* pWdec = (const f16*)(ws + OFF_WDEC);
  const f16* pWl   = (const f16*)(ws + OFF_WL);
  const f16* pUW   = (const f16*)(ws + OFF_UW);

  k_prep<<<200, 256, 0, stream>>>(eWih, eWhh, dWih, dWhh, UW, Wl, ws);
  k_mlp <<<128, 256, 0, stream>>>(ann, W1, b1, W2, b2, hstate);
  k_enc <<<NB / 16, 512, 0, stream>>>(xenc, pWenc, pUW, ebih, ebhh, Ubias,
                                      hstate, encB, uoB);
  k_dec <<<NB / 4, 512, 0, stream>>>(xdec, xenc, pWdec, pWl, dbih, dbhh,
                                     Wlb, Vw, Vb, how, hob, hstate,
                                     encB, uoB, (float*)d_out);
}

// Round 9
// 560.483 us; speedup vs baseline: 2.8929x; 1.0388x over previous
//
#include <hip/hip_runtime.h>
#include <stdint.h>

typedef unsigned int u32;
typedef unsigned short u16;
typedef _Float16 f16;
typedef _Float16 f16x8 __attribute__((ext_vector_type(8)));
typedef _Float16 f16x4 __attribute__((ext_vector_type(4)));
typedef _Float16 f16x2 __attribute__((ext_vector_type(2)));
typedef float f32x4 __attribute__((ext_vector_type(4)));

constexpr int NB = 4096;   // batch
constexpr int NT = 56;     // encoder steps
constexpr int NS = 28;     // decoder steps
constexpr int NH = 126;    // hidden
constexpr int NHP = 128;
constexpr float LOG2E = 1.4426950408889634f;

// decoder LDS row geometry: uoL row 136 elems (%32 words = 4 -> per-t bank rotation)
constexpr int LROW = 136;
constexpr int LB   = NT * LROW + 8;   // 7624

// encT (j-major enc for p3): [b][jp 0..63][t 0..55] f16x2
constexpr int TJP = 120;    // f16 per jp row (56 t * 2 + pad)
constexpr int TB  = 7712;   // f16 per batch (64*120 + pad)

// encoder av row: [ x_p0 20 | pad12 | h_p0 128 | h_p1 128 | pad16 | x_p1 20 | pad12 ]
constexpr int EROW = 344;   // 688 B/row; 172 words %32 = 12 -> conflict-free frag reads

// workspace offsets (bytes)
constexpr size_t OFF_H    = 0;                    // f32[4096*128] h state (pads 0)
constexpr size_t OFF_ENC  = 2097152;              // f16[4096*56*128] enc_out [b][t][h]
constexpr size_t OFF_UO   = OFF_ENC + 58720256;   // f16[4096*56*128] EU=e^(2*Uo) [b][t][h]
constexpr size_t OFF_WENC = OFF_UO + 58720256;    // f16[384*160]  enc gates [x20+pad|h128]
constexpr size_t OFF_WDEC = OFF_WENC + 122880;    // f16[384*288]  dec gates [head16+pad|attn128|h128]
constexpr size_t OFF_WL   = OFF_WDEC + 221184;    // f16[128*128]  Wl
constexpr size_t OFF_UW   = OFF_WL + 32768;       // f16[128*128]  U_W

__device__ __forceinline__ float fexp2(float x){ return __builtin_amdgcn_exp2f(x); }
__device__ __forceinline__ float frcp (float x){ return __builtin_amdgcn_rcpf(x); }
__device__ __forceinline__ float sigm (float x){ return frcp(1.f + fexp2(-LOG2E * x)); }
__device__ __forceinline__ float ftanh(float x){ return 1.f - 2.f * frcp(1.f + fexp2(2.f * LOG2E * x)); }

// ---------------- weight repack ----------------
__global__ void k_prep(const float* __restrict__ eWih, const float* __restrict__ eWhh,
                       const float* __restrict__ dWih, const float* __restrict__ dWhh,
                       const float* __restrict__ UW,   const float* __restrict__ Wl,
                       char* __restrict__ ws)
{
  f16* wenc = (f16*)(ws + OFF_WENC);
  f16* wdec = (f16*)(ws + OFF_WDEC);
  f16* wl   = (f16*)(ws + OFF_WL);
  f16* uw   = (f16*)(ws + OFF_UW);
  const int nE = 384 * 160, nD = 384 * 288, nW = 128 * 128;
  const int total = nE + nD + nW + nW;
  for (int i = blockIdx.x * 256 + threadIdx.x; i < total; i += gridDim.x * 256) {
    int idx = i;
    if (idx < nE) {
      const int r = idx / 160, c = idx % 160;
      float v = 0.f;
      if (r < 378) {
        if (c < 20) v = eWih[r * 20 + c];
        else if (c >= 32 && c < 158) v = eWhh[r * 126 + (c - 32)];
      }
      wenc[idx] = (f16)v; continue;
    }
    idx -= nE;
    if (idx < nD) {
      const int r = idx / 288, c = idx % 288;
      float v = 0.f;
      if (r < 378) {
        if (c < 16) v = dWih[r * 142 + c];
        else if (c >= 32 && c < 158) v = dWih[r * 142 + 16 + (c - 32)];
        else if (c >= 160 && c < 286) v = dWhh[r * 126 + (c - 160)];
      }
      wdec[idx] = (f16)v; continue;
    }
    idx -= nD;
    if (idx < nW) {
      const int r = idx >> 7, c = idx & 127;
      wl[idx] = (f16)((r < 126 && c < 126) ? Wl[r * 126 + c] : 0.f);
      continue;
    }
    idx -= nW;
    { const int r = idx >> 7, c = idx & 127;
      uw[idx] = (f16)((r < 126 && c < 126) ? UW[r * 126 + c] : 0.f); }
  }
}

// ---------------- init MLP ----------------
__global__ __launch_bounds__(256) void k_mlp(
    const float* __restrict__ ann, const float* __restrict__ W1, const float* __restrict__ b1,
    const float* __restrict__ W2, const float* __restrict__ b2, float* __restrict__ hstate)
{
  __shared__ float anns[32][33];
  __shared__ float t1s[32][101];
  const int tid = threadIdx.x;
  const int b0 = blockIdx.x * 32;
  for (int i = tid; i < 32 * 30; i += 256)
    anns[i / 30][i % 30] = ann[(b0 + i / 30) * 30 + (i % 30)];
  __syncthreads();
  const int b = tid & 31, rg = tid >> 5;
  for (int m = rg; m < 96; m += 8) {
    float a = b1[m];
    for (int k = 0; k < 30; ++k) a += W1[m * 30 + k] * anns[b][k];
    t1s[b][m] = fmaxf(a, 0.f);
  }
  __syncthreads();
  for (int j = rg; j < NHP; j += 8) {
    float a = 0.f;
    if (j < NH) {
      a = b2[j];
      for (int k = 0; k < 96; ++k) a += W2[j * 96 + k] * t1s[b][k];
    }
    hstate[(b0 + b) * NHP + j] = a;
  }
}

// ---------------- encoder: MFMA, reg-resident weights, M=16, single barrier/step ----------
// Uo(t-1) merged into step t (A-fragment reuse); x double-buffered via register prefetch.
__global__ __launch_bounds__(512) void k_enc(
    const float* __restrict__ xenc, const f16* __restrict__ Wenc,
    const f16* __restrict__ Uw,
    const float* __restrict__ bih, const float* __restrict__ bhh,
    const float* __restrict__ Ub,
    float* __restrict__ hstate, f16* __restrict__ encO, u16* __restrict__ uoO)
{
  __shared__ f16 av[16][EROW];
  const int tid = threadIdx.x;
  const int wid = tid >> 6, l = tid & 63, quad = l >> 4, col = l & 15;
  const int b0 = blockIdx.x * 16;
  const int jb = wid * 16, j = jb + col;
  const bool valid = j < NH;
  const int jc = valid ? j : NH - 1;

  const float br  = bih[jc]        + bhh[jc];
  const float bz  = bih[NH + jc]   + bhh[NH + jc];
  const float bnx = bih[2*NH + jc];
  const float bnh = bhh[2*NH + jc];
  const float ub  = Ub[jc];

  f16x8 rB[5], zB[5], nxB, nhB[4], uB[4];
  {
    const int ko = quad * 8, rr = jb + col;
#pragma unroll
    for (int kt = 0; kt < 5; ++kt) {
      rB[kt] = *(const f16x8*)&Wenc[rr * 160 + kt * 32 + ko];
      zB[kt] = *(const f16x8*)&Wenc[(NH + rr) * 160 + kt * 32 + ko];
    }
    nxB = *(const f16x8*)&Wenc[(2*NH + rr) * 160 + ko];
#pragma unroll
    for (int kt = 0; kt < 4; ++kt) {
      nhB[kt] = *(const f16x8*)&Wenc[(2*NH + rr) * 160 + 32 + kt * 32 + ko];
      uB[kt]  = *(const f16x8*)&Uw[rr * 128 + kt * 32 + ko];
    }
  }

  {  // h(0) into parity-0 [32..160)
    const int bb = tid >> 5, c4 = (tid & 31) * 4;
    const float4 hv = *(const float4*)&hstate[(b0 + bb) * NHP + c4];
    av[bb][32 + c4]     = (f16)hv.x; av[bb][32 + c4 + 1] = (f16)hv.y;
    av[bb][32 + c4 + 2] = (f16)hv.z; av[bb][32 + c4 + 3] = (f16)hv.w;
  }
  if (tid < 384) {  // zero x-tails of both parities: [20,32) and [324,336)
    const int bb = tid / 24, p = tid % 24;
    av[bb][(p < 12) ? (20 + p) : (312 + p)] = (f16)0.f;
  }
  const int bb320 = tid / 20, e320 = tid % 20;
  if (tid < 320)   // x(0) into parity-0 [0..20)
    av[bb320][e320] = (f16)xenc[((size_t)0 * NB + b0 + bb320) * 20 + e320];
  __syncthreads();

  const int m = col, ko = quad * 8;
  for (int t = 0; t < NT; ++t) {
    const int hp = 32 + (t & 1) * 128, hq = 32 + ((t + 1) & 1) * 128;
    const int xp = (t & 1) ? 304 : 0,  xq = ((t + 1) & 1) ? 304 : 0;

    // prefetch x(t+1) from global (latency hidden under the MFMAs below)
    float xv = 0.f;
    const bool ldx = (tid < 320) && (t + 1 < NT);
    if (ldx) xv = xenc[((size_t)(t + 1) * NB + b0 + bb320) * 20 + e320];

    f16x8 A[5];
    A[0] = *(const f16x8*)&av[m][xp + ko];
#pragma unroll
    for (int kt = 1; kt < 5; ++kt) A[kt] = *(const f16x8*)&av[m][hp + (kt - 1) * 32 + ko];

    // Uo for step t-1: enc_out(t-1) == h(t) == A[1..4] (free fragment reuse)
    if (t) {
      f32x4 Cu = {ub, ub, ub, ub};
#pragma unroll
      for (int kt = 0; kt < 4; ++kt)
        Cu = __builtin_amdgcn_mfma_f32_16x16x32_f16(A[kt + 1], uB[kt], Cu, 0, 0, 0);
#pragma unroll
      for (int c = 0; c < 4; ++c) {
        union { f16 h; u16 u; } cv;
        cv.h = (f16)fexp2(2.f * LOG2E * Cu[c]);         // EU = e^(2*Uo), f16
        uoO[((size_t)(b0 + quad * 4 + c) * NT + (t - 1)) * 128 + j] = valid ? cv.u : (u16)0;
      }
    }

    f32x4 Cr = {br, br, br, br}, Cz = {bz, bz, bz, bz};
    f32x4 Cnx = {bnx, bnx, bnx, bnx}, Cnh = {bnh, bnh, bnh, bnh};
#pragma unroll
    for (int kt = 0; kt < 5; ++kt) {
      Cr = __builtin_amdgcn_mfma_f32_16x16x32_f16(A[kt], rB[kt], Cr, 0, 0, 0);
      Cz = __builtin_amdgcn_mfma_f32_16x16x32_f16(A[kt], zB[kt], Cz, 0, 0, 0);
    }
    Cnx = __builtin_amdgcn_mfma_f32_16x16x32_f16(A[0], nxB, Cnx, 0, 0, 0);
#pragma unroll
    for (int kt = 0; kt < 4; ++kt)
      Cnh = __builtin_amdgcn_mfma_f32_16x16x32_f16(A[kt + 1], nhB[kt], Cnh, 0, 0, 0);

    float hv4[4];
#pragma unroll
    for (int c = 0; c < 4; ++c) {
      const int bb = quad * 4 + c;
      const float hold = (float)av[bb][hp + j];
      const float r = sigm(Cr[c]), z = sigm(Cz[c]);
      const float n = ftanh(Cnx[c] + r * Cnh[c]);
      hv4[c] = (1.f - z) * n + z * hold;
    }
#pragma unroll
    for (int c = 0; c < 4; ++c) {
      const int bb = quad * 4 + c;
      const f16 hs = valid ? (f16)hv4[c] : (f16)0.f;
      av[bb][hq + j] = hs;
      encO[((size_t)(b0 + bb) * NT + t) * 128 + j] = hs;
    }
    if (t == NT - 1 && valid) {
#pragma unroll
      for (int c = 0; c < 4; ++c)
        hstate[(b0 + quad * 4 + c) * NHP + j] = hv4[c];
    }
    if (ldx) av[bb320][xq + e320] = (f16)xv;
    __syncthreads();                       // single barrier per step
  }

  // Uo for the last step (h(NT) is in parity NT&1 == 0; ordered by the final barrier)
  {
    f16x8 Ah[4];
#pragma unroll
    for (int kt = 0; kt < 4; ++kt) Ah[kt] = *(const f16x8*)&av[m][32 + kt * 32 + ko];
    f32x4 Cu = {ub, ub, ub, ub};
#pragma unroll
    for (int kt = 0; kt < 4; ++kt)
      Cu = __builtin_amdgcn_mfma_f32_16x16x32_f16(Ah[kt], uB[kt], Cu, 0, 0, 0);
#pragma unroll
    for (int c = 0; c < 4; ++c) {
      union { f16 h; u16 u; } cv;
      cv.h = (f16)fexp2(2.f * LOG2E * Cu[c]);
      uoO[((size_t)(b0 + quad * 4 + c) * NT + (NT - 1)) * 128 + j] = valid ? cv.u : (u16)0;
    }
  }
}

// ---------------- decoder: M=4 at A-rows {0,4,8,12}, 512 threads, LDS-resident EU+enc ------
// R3/R7 structure + barrier-drain pipelining: the only global ops in steady state (xdec
// load, out store) are issued right AFTER B1 so their vmcnt(0) drain lands at B2, hidden
// behind p2 (the longest phase). B1's drain becomes LDS-only.
__global__ __launch_bounds__(512, 2) void k_dec(
    const float* __restrict__ xdec, const float* __restrict__ xenc,
    const f16* __restrict__ Wdec, const f16* __restrict__ WlW,
    const float* __restrict__ bih, const float* __restrict__ bhh,
    const float* __restrict__ Wlb, const float* __restrict__ Vw,
    const float* __restrict__ Vb, const float* __restrict__ how,
    const float* __restrict__ hob, const float* __restrict__ hstate,
    const f16* __restrict__ encO, const u16* __restrict__ uoO,
    float* __restrict__ out)
{
  __shared__ __align__(16) u16 uoL[4 * LB];      // EU f16 bits, 61.0 KB, t-major
  __shared__ __align__(16) f16 encT[4 * TB];     // enc f16, 61.7 KB, j-major
  __shared__ __align__(16) f16 av[5][424];       // [b][head16+pad16|attn128|h_p0|h_p1|pad]; row4=0
  __shared__ float EWS[4][132];                  // e^(2*Wh)
  __shared__ float scS[4][60];                   // exp(score)
  __shared__ __align__(16) f16 hows16[128];
  const int tid = threadIdx.x;
  const int wid = tid >> 6, l = tid & 63, quad = l >> 4, col = l & 15;
  const int b0 = blockIdx.x * 4;
  const int jb = wid * 16, j = jb + col;
  const bool valid = j < NH;
  const int jc = valid ? j : NH - 1;

  const float br  = bih[jc]        + bhh[jc];
  const float bz  = bih[NH + jc]   + bhh[NH + jc];
  const float bnx = bih[2*NH + jc];
  const float bnh = bhh[2*NH + jc];
  const float wb  = Wlb[jc];
  const float vb0 = Vb[0], hob0 = hob[0];

  // xdec register pipeline (tid<60): holds x(s+1) across the step
  const int xb = tid / 15, xe = tid % 15;
  float xv = 0.f;
  if (tid < 60) xv = xdec[((size_t)0 * NB + b0 + xb) * 15 + xe];

  f16x8 rB[9], zB[9], nxB[5], nhB[4], wlB[4];
  {
    const int ko = quad * 8, rr = jb + col;
#pragma unroll
    for (int kt = 0; kt < 9; ++kt) {
      rB[kt] = *(const f16x8*)&Wdec[rr * 288 + kt * 32 + ko];
      zB[kt] = *(const f16x8*)&Wdec[(NH + rr) * 288 + kt * 32 + ko];
    }
#pragma unroll
    for (int kt = 0; kt < 5; ++kt)
      nxB[kt] = *(const f16x8*)&Wdec[(2*NH + rr) * 288 + kt * 32 + ko];
#pragma unroll
    for (int kt = 0; kt < 4; ++kt) {
      nhB[kt] = *(const f16x8*)&Wdec[(2*NH + rr) * 288 + 160 + kt * 32 + ko];
      wlB[kt] = *(const f16x8*)&WlW[rr * 128 + kt * 32 + ko];
    }
  }

  const int g = tid >> 3, sub = tid & 7;
  float n2v[16], svsum = 0.f;
#pragma unroll
  for (int i = 0; i < 16; ++i) {
    const int jj = sub * 16 + i;
    const float v = (jj < NH) ? Vw[jj] : 0.f;
    n2v[i] = -2.f * v;
    svsum += v;
  }
  if (tid >= 256 && tid < 384) {
    const int q = tid - 256; hows16[q] = (f16)((q < NH) ? how[q] : 0.f);
  }
  for (int i = tid; i < 5 * 424; i += 512) av[i / 424][i % 424] = (f16)0.f;
  if (tid < 24) EWS[tid / 6][126 + tid % 6] = 0.f;   // pad cols stay 0 (avoid NaN)
  {
    const size_t gb = (size_t)b0 * NT * 128;
    for (int i = tid; i < 4 * NT * 16; i += 512) {
      const int ch = i & 15, btr = i >> 4;
      const int bb = btr / NT, tt = btr % NT;
      const size_t src = gb + (size_t)btr * 128 + ch * 8;
      *(f16x8*)&uoL[bb * LB + tt * LROW + ch * 8] = *(const f16x8*)&uoO[src];
      const f16x8 ev = *(const f16x8*)&encO[src];
#pragma unroll
      for (int k2 = 0; k2 < 4; ++k2) {   // transpose to j-major: jp = ch*4+k2
        f16x2 pr; pr[0] = ev[2 * k2]; pr[1] = ev[2 * k2 + 1];
        *(f16x2*)&encT[bb * TB + (ch * 4 + k2) * TJP + tt * 2] = pr;
      }
    }
  }
  __syncthreads();
  if (tid < 128) {   // h0 rows 0..3 into parity-0 [160..288)
    const int bb = tid >> 5, c4 = (tid & 31) * 4;
    const float4 hv = *(const float4*)&hstate[(b0 + bb) * NHP + c4];
    av[bb][160 + c4]     = (f16)hv.x; av[bb][160 + c4 + 1] = (f16)hv.y;
    av[bb][160 + c4 + 2] = (f16)hv.z; av[bb][160 + c4 + 3] = (f16)hv.w;
  }
  if (tid < 4) av[tid][0] = (f16)xenc[((size_t)(NT - 1) * NB + b0 + tid) * 20];  // gt0
  __syncthreads();

  const int m = col, ko = quad * 8;
  // batch b feeds A-row 4b; rows with m%4!=0 read the zero row 4
  const int arow = ((m & 3) == 0) ? (m >> 2) : 4;
  const int pb = tid & 3, pth = (tid >> 2) & 1, pjp = tid >> 3;   // p3 map
  float oPrev = 0.f;

  for (int s = 0; s < NS; ++s) {
    const int hp = 160 + (s & 1) * 128, hq = 160 + ((s + 1) & 1) * 128;

    // p1: Wh -> EW = e^(2*Wh) (MFMA); merged p5 (out for s-1, store deferred past B1);
    // stage dec_x from the register pipeline (LDS write only, no global op).
    {
      f16x8 Ah[4];
#pragma unroll
      for (int kt = 0; kt < 4; ++kt) Ah[kt] = *(const f16x8*)&av[arow][hp + kt * 32 + ko];
      f32x4 Cw = {wb, wb, wb, wb};
#pragma unroll
      for (int kt = 0; kt < 4; ++kt)
        Cw = __builtin_amdgcn_mfma_f32_16x16x32_f16(Ah[kt], wlB[kt], Cw, 0, 0, 0);
      if (valid) EWS[quad][j] = fexp2(2.f * LOG2E * Cw[0]);
      if (wid == 0 && s > 0) {           // p5 for previous step: hp(s) == hq(s-1)
        f16x8 hB[4];
        const f16x8 zz = {};
#pragma unroll
        for (int kt = 0; kt < 4; ++kt)
          hB[kt] = (col == 0) ? *(const f16x8*)&hows16[kt * 32 + ko] : zz;
        f32x4 Co = {0.f, 0.f, 0.f, 0.f};
#pragma unroll
        for (int kt = 0; kt < 4; ++kt)
          Co = __builtin_amdgcn_mfma_f32_16x16x32_f16(Ah[kt], hB[kt], Co, 0, 0, 0);
        if (col == 0) {
          oPrev = Co[0] + hob0;
          av[quad][0] = (f16)oPrev;      // prev feedback; ordered by B1..B3 before p4
        }
      }
    }
    if (tid < 60) av[xb][1 + xe] = (f16)xv;
    __syncthreads();  // B1 (LDS-only drain)

    // issue next-step global ops here: their vmcnt(0) drain lands at B2, behind p2
    if (wid == 0 && s > 0 && col == 0)
      out[(size_t)(s - 1) * NB + b0 + quad] = oPrev;
    if (tid < 60 && s + 1 < NS)
      xv = xdec[((size_t)(s + 1) * NB + b0 + xb) * 15 + xe];

    // p2: scores via svsum + sum(-2v/(1+EU*EW)); 64 groups = 4b x 16 t-base, 4 rounds
    // accumulated into rs[4]; ONE interleaved reduce tree after all rounds.
    {
      const int sbb = g & 3, tb = g >> 2;
      float ew[16];
#pragma unroll
      for (int i = 0; i < 4; ++i)
        *(float4*)&ew[i * 4] = *(const float4*)&EWS[sbb][sub * 16 + i * 4];
      const u16* up0 = &uoL[sbb * LB + sub * 16];
      uint4 q0 = *(const uint4*)&up0[tb * LROW];
      uint4 q1 = *(const uint4*)&up0[tb * LROW + 8];
      float rs[4];
#pragma unroll
      for (int rd = 0; rd < 4; ++rd) {
        const int t = rd * 16 + tb;
        const u32 wsv[8] = {q0.x, q0.y, q0.z, q0.w, q1.x, q1.y, q1.z, q1.w};
        if (rd < 3) {
          const int tn = (t + 16 < NT) ? (t + 16) : (NT - 1);
          q0 = *(const uint4*)&up0[tn * LROW];
          q1 = *(const uint4*)&up0[tn * LROW + 8];
        }
        float ac0 = 0.f, ac1 = 0.f, ac2 = 0.f, ac3 = 0.f;
#pragma unroll
        for (int k = 0; k < 8; k += 2) {
          union { u32 i; f16x2 h; } ua, ub2;
          ua.i = wsv[k]; ub2.i = wsv[k + 1];
          const float p0 = fmaf((float)ua.h[0],  ew[2 * k],     1.f);
          const float p1 = fmaf((float)ua.h[1],  ew[2 * k + 1], 1.f);
          const float p2 = fmaf((float)ub2.h[0], ew[2 * k + 2], 1.f);
          const float p3 = fmaf((float)ub2.h[1], ew[2 * k + 3], 1.f);
          ac0 = fmaf(n2v[2 * k],     frcp(p0), ac0);
          ac1 = fmaf(n2v[2 * k + 1], frcp(p1), ac1);
          ac2 = fmaf(n2v[2 * k + 2], frcp(p2), ac2);
          ac3 = fmaf(n2v[2 * k + 3], frcp(p3), ac3);
        }
        rs[rd] = svsum + (ac0 + ac1) + (ac2 + ac3);
      }
      rs[0] += __shfl_xor(rs[0], 1, 64);
      rs[1] += __shfl_xor(rs[1], 1, 64);
      rs[2] += __shfl_xor(rs[2], 1, 64);
      rs[3] += __shfl_xor(rs[3], 1, 64);
      rs[0] += __shfl_xor(rs[0], 2, 64);
      rs[1] += __shfl_xor(rs[1], 2, 64);
      rs[2] += __shfl_xor(rs[2], 2, 64);
      rs[3] += __shfl_xor(rs[3], 2, 64);
      rs[0] += __shfl_xor(rs[0], 4, 64);
      rs[1] += __shfl_xor(rs[1], 4, 64);
      rs[2] += __shfl_xor(rs[2], 4, 64);
      rs[3] += __shfl_xor(rs[3], 4, 64);
      if (sub == 0) {
#pragma unroll
        for (int rd = 0; rd < 4; ++rd) {
          const int t = rd * 16 + tb;
          if (t < NT) scS[sbb][t] = fexp2(LOG2E * (rs[rd] + vb0));
        }
      }
    }
    __syncthreads();  // B2

    // p3: softmax + attn; thread = (batch, pth t-half, j-pair); 7 wide b128 reads of encT
    {
      const int j0 = pjp * 2;
      const f16* er = &encT[pb * TB + pjp * TJP + pth * 56];
      const float* scp = &scS[pb][pth * 28];
      float Za = 0.f, Zb = 0.f;
      float a0a = 0.f, a0b = 0.f, a1a = 0.f, a1b = 0.f;
#pragma unroll
      for (int it = 0; it < 7; ++it) {
        const f16x8 ev = *(const f16x8*)&er[it * 8];
        const float4 sc = *(const float4*)&scp[it * 4];
        Za += sc.x; Zb += sc.y; Za += sc.z; Zb += sc.w;
        a0a = fmaf(sc.x, (float)ev[0], a0a);
        a1a = fmaf(sc.x, (float)ev[1], a1a);
        a0b = fmaf(sc.y, (float)ev[2], a0b);
        a1b = fmaf(sc.y, (float)ev[3], a1b);
        a0a = fmaf(sc.z, (float)ev[4], a0a);
        a1a = fmaf(sc.z, (float)ev[5], a1a);
        a0b = fmaf(sc.w, (float)ev[6], a0b);
        a1b = fmaf(sc.w, (float)ev[7], a1b);
      }
      float Z = Za + Zb, a0 = a0a + a0b, a1 = a1a + a1b;
      a0 += __shfl_xor(a0, 4, 64);
      a1 += __shfl_xor(a1, 4, 64);
      Z  += __shfl_xor(Z, 4, 64);
      if (pth == 0) {
        const float inv = frcp(Z);
        f16x2 st; st[0] = (f16)(a0 * inv); st[1] = (f16)(a1 * inv);
        *(f16x2*)&av[pb][32 + j0] = st;
      }
    }
    __syncthreads();  // B3

    // p4: GRU gates (MFMA) + state update; every lane handles one (batch=quad, j) elem
    {
      f16x8 A[9];
#pragma unroll
      for (int kt = 0; kt < 5; ++kt) A[kt] = *(const f16x8*)&av[arow][kt * 32 + ko];
#pragma unroll
      for (int kt = 5; kt < 9; ++kt) A[kt] = *(const f16x8*)&av[arow][hp + (kt - 5) * 32 + ko];
      f32x4 Cr = {br, br, br, br}, Cz = {bz, bz, bz, bz};
      f32x4 Cnx = {bnx, bnx, bnx, bnx}, Cnh = {bnh, bnh, bnh, bnh};
#pragma unroll
      for (int kt = 0; kt < 9; ++kt) {
        Cr = __builtin_amdgcn_mfma_f32_16x16x32_f16(A[kt], rB[kt], Cr, 0, 0, 0);
        Cz = __builtin_amdgcn_mfma_f32_16x16x32_f16(A[kt], zB[kt], Cz, 0, 0, 0);
      }
#pragma unroll
      for (int kt = 0; kt < 5; ++kt)
        Cnx = __builtin_amdgcn_mfma_f32_16x16x32_f16(A[kt], nxB[kt], Cnx, 0, 0, 0);
#pragma unroll
      for (int kt = 0; kt < 4; ++kt)
        Cnh = __builtin_amdgcn_mfma_f32_16x16x32_f16(A[kt + 5], nhB[kt], Cnh, 0, 0, 0);
      {
        const float hold = (float)av[quad][hp + j];
        const float r = sigm(Cr[0]), z = sigm(Cz[0]);
        const float n = ftanh(Cnx[0] + r * Cnh[0]);
        const float h2 = (1.f - z) * n + z * hold;
        if (valid) av[quad][hq + j] = (f16)h2;
      }
    }
    __syncthreads();  // B4
  }

  // epilogue p5 for s = NS-1 (B4 of last iter orders p4 writes before these reads)
  if (wid == 0) {
    const int hql = 160 + (NS & 1) * 128;
    f16x8 Ah2[4], hB[4];
    const f16x8 zz = {};
#pragma unroll
    for (int kt = 0; kt < 4; ++kt) {
      Ah2[kt] = *(const f16x8*)&av[arow][hql + kt * 32 + ko];
      hB[kt] = (col == 0) ? *(const f16x8*)&hows16[kt * 32 + ko] : zz;
    }
    f32x4 Co = {0.f, 0.f, 0.f, 0.f};
#pragma unroll
    for (int kt = 0; kt < 4; ++kt)
      Co = __builtin_amdgcn_mfma_f32_16x16x32_f16(Ah2[kt], hB[kt], Co, 0, 0, 0);
    if (col == 0) out[(size_t)(NS - 1) * NB + b0 + quad] = Co[0] + hob0;
  }
}

extern "C" void kernel_launch(void* const* d_in, const int* in_sizes, int n_in,
                              void* d_out, int out_size, void* d_ws, size_t ws_size,
                              hipStream_t stream)
{
  const float* ann   = (const float*)d_in[0];
  const float* xenc  = (const float*)d_in[1];
  const float* xdec  = (const float*)d_in[2];
  const float* W1    = (const float*)d_in[3];
  const float* b1    = (const float*)d_in[4];
  const float* W2    = (const float*)d_in[5];
  const float* b2    = (const float*)d_in[6];
  const float* eWih  = (const float*)d_in[7];
  const float* eWhh  = (const float*)d_in[8];
  const float* ebih  = (const float*)d_in[9];
  const float* ebhh  = (const float*)d_in[10];
  const float* dWih  = (const float*)d_in[11];
  const float* dWhh  = (const float*)d_in[12];
  const float* dbih  = (const float*)d_in[13];
  const float* dbhh  = (const float*)d_in[14];
  const float* UW    = (const float*)d_in[15];
  const float* Ubias = (const float*)d_in[16];
  const float* Wl    = (const float*)d_in[17];
  const float* Wlb   = (const float*)d_in[18];
  const float* Vw    = (const float*)d_in[19];
  const float* Vb    = (const float*)d_in[20];
  const float* how   = (const float*)d_in[21];
  const float* hob   = (const float*)d_in[22];

  char* ws = (char*)d_ws;
  float* hstate = (float*)(ws + OFF_H);
  f16*   encB   = (f16*)(ws + OFF_ENC);
  u16*   uoB    = (u16*)(ws + OFF_UO);
  const f16* pWenc = (const f16*)(ws + OFF_WENC);
  const f16* pWdec = (const f16*)(ws + OFF_WDEC);
  const f16* pWl   = (const f16*)(ws + OFF_WL);
  const f16* pUW   = (const f16*)(ws + OFF_UW);

  k_prep<<<200, 256, 0, stream>>>(eWih, eWhh, dWih, dWhh, UW, Wl, ws);
  k_mlp <<<128, 256, 0, stream>>>(ann, W1, b1, W2, b2, hstate);
  k_enc <<<NB / 16, 512, 0, stream>>>(xenc, pWenc, pUW, ebih, ebhh, Ubias,
                                      hstate, encB, uoB);
  k_dec <<<NB / 4, 512, 0, stream>>>(xdec, xenc, pWdec, pWl, dbih, dbhh,
                                     Wlb, Vw, Vb, how, hob, hstate,
                                     encB, uoB, (float*)d_out);
}